// Round 1
// baseline (233.822 us; speedup 1.0000x reference)
//
#include <hip/hip_runtime.h>

#define DIM 768
#define NTOK 4096
#define HID 3072

typedef __attribute__((ext_vector_type(8))) short bf16x8;
typedef __attribute__((ext_vector_type(4))) float f32x4;

__device__ inline unsigned short f2bf(float f){
  unsigned u = __float_as_uint(f);
  u += 0x7fff + ((u >> 16) & 1);
  return (unsigned short)(u >> 16);
}

// ---------------- LayerNorm: fp32 in -> bf16 out, 1 wave per 768-row ----------------
__global__ __launch_bounds__(256) void ln_kernel(const float* __restrict__ x,
    const float* __restrict__ g, const float* __restrict__ b,
    unsigned short* __restrict__ out)
{
  int row = blockIdx.x * 4 + (threadIdx.x >> 6);
  int lane = threadIdx.x & 63;
  const float* xr = x + (size_t)row * DIM;
  float4 v[3];
  float s = 0.f, s2 = 0.f;
#pragma unroll
  for (int j = 0; j < 3; ++j){
    v[j] = *(const float4*)(xr + j * 256 + lane * 4);
    s  += v[j].x + v[j].y + v[j].z + v[j].w;
    s2 += v[j].x*v[j].x + v[j].y*v[j].y + v[j].z*v[j].z + v[j].w*v[j].w;
  }
#pragma unroll
  for (int m = 1; m < 64; m <<= 1){ s += __shfl_xor(s, m, 64); s2 += __shfl_xor(s2, m, 64); }
  float mu  = s * (1.f / 768.f);
  float var = s2 * (1.f / 768.f) - mu * mu;
  float inv = rsqrtf(var + 1e-5f);
#pragma unroll
  for (int j = 0; j < 3; ++j){
    int c0 = j * 256 + lane * 4;
    float vv[4] = { v[j].x, v[j].y, v[j].z, v[j].w };
    ushort4 o4;
    o4.x = f2bf((vv[0] - mu) * inv * g[c0 + 0] + b[c0 + 0]);
    o4.y = f2bf((vv[1] - mu) * inv * g[c0 + 1] + b[c0 + 1]);
    o4.z = f2bf((vv[2] - mu) * inv * g[c0 + 2] + b[c0 + 2]);
    o4.w = f2bf((vv[3] - mu) * inv * g[c0 + 3] + b[c0 + 3]);
    *(ushort4*)(out + (size_t)row * DIM + c0) = o4;
  }
}

// ---------------- Transpose + bf16 cast: W[K][N] fp32 -> Wt[N][K] bf16 ----------------
__global__ __launch_bounds__(256) void transpose_kernel(const float* __restrict__ W,
    unsigned short* __restrict__ Wt, int K, int N)
{
  __shared__ __align__(16) unsigned short tile[32][33];
  int n0 = blockIdx.x * 32, k0 = blockIdx.y * 32;
  int tx = threadIdx.x & 31, ty = threadIdx.x >> 5;
#pragma unroll
  for (int i = 0; i < 32; i += 8)
    tile[ty + i][tx] = f2bf(W[(size_t)(k0 + ty + i) * N + n0 + tx]);
  __syncthreads();
#pragma unroll
  for (int i = 0; i < 32; i += 8)
    Wt[(size_t)(n0 + ty + i) * K + k0 + tx] = tile[tx][ty + i];
}

// ---------------- Generic MFMA GEMM: C[M][N] = A[M][K] @ Bt[N][K]^T + bias (+epi) ----
// EPI: 0 = bias only, 1 = bias + exact GELU, 2 = bias + residual add
template<int BM, int EPI, typename OutT>
__global__ __launch_bounds__(256) void gemm_kernel(
    const unsigned short* __restrict__ A,   // [M][K] bf16
    const unsigned short* __restrict__ Bt,  // [N][K] bf16
    const float* __restrict__ bias,         // [N]
    const float* __restrict__ resid,        // [M][N] (EPI==2)
    OutT* __restrict__ C,                   // [M][N]
    int M, int N, int K)
{
  static_assert(BM == 64 || BM == 128, "");
  constexpr int LD = 40;           // 32 + 8 pad (row stride 80B, 16B-aligned)
  constexpr int MI = BM / 32;      // frags per wave per dim
  __shared__ __align__(16) unsigned short As[BM * LD];
  __shared__ __align__(16) unsigned short Bs[BM * LD];
  const int t = threadIdx.x;
  const int lane = t & 63, wid = t >> 6;
  const int lo = lane & 15, hi = lane >> 4;
  const int wr = wid >> 1, wc = wid & 1;
  const int bm = blockIdx.y * BM, bn = blockIdx.x * BM;

  f32x4 acc[MI][MI];
#pragma unroll
  for (int i = 0; i < MI; ++i)
#pragma unroll
    for (int j = 0; j < MI; ++j) acc[i][j] = (f32x4){0.f, 0.f, 0.f, 0.f};

  for (int k0 = 0; k0 < K; k0 += 32){
    __syncthreads();   // protect previous iteration's frag reads
#pragma unroll
    for (int u = 0; u < BM / 64; ++u){
      int e = t + u * 256;
      int srow = e >> 2, scol = (e & 3) * 8;
      *(bf16x8*)&As[srow * LD + scol] = *(const bf16x8*)(A  + (size_t)(bm + srow) * K + k0 + scol);
      *(bf16x8*)&Bs[srow * LD + scol] = *(const bf16x8*)(Bt + (size_t)(bn + srow) * K + k0 + scol);
    }
    __syncthreads();
    bf16x8 af[MI], bfr[MI];
#pragma unroll
    for (int i = 0; i < MI; ++i) af[i]  = *(const bf16x8*)&As[(wr * (BM/2) + i * 16 + lo) * LD + hi * 8];
#pragma unroll
    for (int j = 0; j < MI; ++j) bfr[j] = *(const bf16x8*)&Bs[(wc * (BM/2) + j * 16 + lo) * LD + hi * 8];
#pragma unroll
    for (int i = 0; i < MI; ++i)
#pragma unroll
      for (int j = 0; j < MI; ++j)
        acc[i][j] = __builtin_amdgcn_mfma_f32_16x16x32_bf16(af[i], bfr[j], acc[i][j], 0, 0, 0);
  }

  // epilogue: C/D layout col = lane&15, row = (lane>>4)*4 + r  [verified m89/m91]
#pragma unroll
  for (int i = 0; i < MI; ++i){
#pragma unroll
    for (int j = 0; j < MI; ++j){
      int col = bn + wc * (BM/2) + j * 16 + lo;
      float bcol = bias[col];
#pragma unroll
      for (int r = 0; r < 4; ++r){
        int row = bm + wr * (BM/2) + i * 16 + hi * 4 + r;
        float v = acc[i][j][r] + bcol;
        if constexpr (EPI == 1) v = 0.5f * v * (1.f + erff(v * 0.70710678118f));
        if constexpr (EPI == 2) v += resid[(size_t)row * N + col];
        if constexpr (sizeof(OutT) == 2) C[(size_t)row * N + col] = f2bf(v);
        else                             C[(size_t)row * N + col] = v;
      }
    }
  }
}

// ---------------- Flash-style attention ----------------
// grid (qb=16, h=12, b=4), 256 threads = 4 waves; wave w owns q-rows qb*64+w*16..+16
__global__ __launch_bounds__(256) void attn_kernel(const unsigned short* __restrict__ qkv,
    const int* __restrict__ amask, unsigned short* __restrict__ o)
{
  constexpr int LD = 72;  // 64 + 8 pad, row stride 144B (16B-aligned)
  __shared__ __align__(16) unsigned short Kl[64 * LD];
  __shared__ __align__(16) unsigned short Vt[64 * LD];   // transposed: [d][key]
  __shared__ __align__(16) unsigned short Pl[4][16 * LD];
  const int qb = blockIdx.x, h = blockIdx.y, b = blockIdx.z;
  const int t = threadIdx.x, wid = t >> 6, lane = t & 63;
  const int lo = lane & 15, hi = lane >> 4;
  const size_t LDQ = 2304;

  // Q fragments held in registers for the whole kernel
  const int qrow = b * 1024 + qb * 64 + wid * 16 + lo;
  bf16x8 qf[2];
#pragma unroll
  for (int kk = 0; kk < 2; ++kk)
    qf[kk] = *(const bf16x8*)(qkv + (size_t)qrow * LDQ + h * 64 + kk * 32 + hi * 8);

  f32x4 oacc[4];
#pragma unroll
  for (int dj = 0; dj < 4; ++dj) oacc[dj] = (f32x4){0.f, 0.f, 0.f, 0.f};
  float m_r[4], l_r[4];
#pragma unroll
  for (int i = 0; i < 4; ++i){ m_r[i] = -1e30f; l_r[i] = 0.f; }

  const int srow = t >> 2, scol = (t & 3) * 16;
  for (int kt = 0; kt < 16; ++kt){
    __syncthreads();   // previous iteration's LDS reads complete
    // stage K tile [64 keys][64 d] as-is; V tile transposed into Vt[d][key]
    const unsigned short* Kg = qkv + (size_t)(b * 1024 + kt * 64 + srow) * LDQ + 768 + h * 64 + scol;
    *(bf16x8*)&Kl[srow * LD + scol]     = *(const bf16x8*)Kg;
    *(bf16x8*)&Kl[srow * LD + scol + 8] = *(const bf16x8*)(Kg + 8);
    const unsigned short* Vg = qkv + (size_t)(b * 1024 + kt * 64 + srow) * LDQ + 1536 + h * 64 + scol;
#pragma unroll
    for (int e = 0; e < 16; ++e) Vt[(scol + e) * LD + srow] = Vg[e];
    __syncthreads();

    // S = Q @ K^T  (16 q-rows x 64 keys per wave)
    f32x4 s[4];
#pragma unroll
    for (int nj = 0; nj < 4; ++nj) s[nj] = (f32x4){0.f, 0.f, 0.f, 0.f};
#pragma unroll
    for (int nj = 0; nj < 4; ++nj)
#pragma unroll
      for (int kk = 0; kk < 2; ++kk){
        bf16x8 kf = *(const bf16x8*)&Kl[(nj * 16 + lo) * LD + kk * 32 + hi * 8];
        s[nj] = __builtin_amdgcn_mfma_f32_16x16x32_bf16(qf[kk], kf, s[nj], 0, 0, 0);
      }
    // scale + mask bias
#pragma unroll
    for (int nj = 0; nj < 4; ++nj){
      int key = kt * 64 + nj * 16 + lo;
      float mb = (amask[b * 1024 + key] == 0) ? -10000.f : 0.f;
#pragma unroll
      for (int i = 0; i < 4; ++i) s[nj][i] = s[nj][i] * 0.125f + mb;
    }
    // online softmax (row r = hi*4+i lives across the 16 lanes sharing hi)
#pragma unroll
    for (int i = 0; i < 4; ++i){
      float pm = fmaxf(fmaxf(s[0][i], s[1][i]), fmaxf(s[2][i], s[3][i]));
#pragma unroll
      for (int m = 1; m < 16; m <<= 1) pm = fmaxf(pm, __shfl_xor(pm, m, 64));
      float mnew = fmaxf(m_r[i], pm);
      float scl = __expf(m_r[i] - mnew);
      m_r[i] = mnew;
      l_r[i] *= scl;
#pragma unroll
      for (int dj = 0; dj < 4; ++dj) oacc[dj][i] *= scl;
      float ps = 0.f;
#pragma unroll
      for (int nj = 0; nj < 4; ++nj){ float p = __expf(s[nj][i] - mnew); s[nj][i] = p; ps += p; }
#pragma unroll
      for (int m = 1; m < 16; m <<= 1) ps += __shfl_xor(ps, m, 64);
      l_r[i] += ps;
    }
    // P (C-layout) -> LDS -> A-fragment layout
    unsigned short* pw = &Pl[wid][0];
#pragma unroll
    for (int nj = 0; nj < 4; ++nj)
#pragma unroll
      for (int i = 0; i < 4; ++i)
        pw[(hi * 4 + i) * LD + nj * 16 + lo] = f2bf(s[nj][i]);
    __syncthreads();
    bf16x8 pf[2];
#pragma unroll
    for (int kk = 0; kk < 2; ++kk) pf[kk] = *(const bf16x8*)&pw[lo * LD + kk * 32 + hi * 8];
    // O += P @ V
#pragma unroll
    for (int dj = 0; dj < 4; ++dj)
#pragma unroll
      for (int kk = 0; kk < 2; ++kk){
        bf16x8 vf = *(const bf16x8*)&Vt[(dj * 16 + lo) * LD + kk * 32 + hi * 8];
        oacc[dj] = __builtin_amdgcn_mfma_f32_16x16x32_bf16(pf[kk], vf, oacc[dj], 0, 0, 0);
      }
  }
  // normalize + write o[token][h*64+d]
#pragma unroll
  for (int dj = 0; dj < 4; ++dj){
    int col = h * 64 + dj * 16 + lo;
#pragma unroll
    for (int i = 0; i < 4; ++i){
      int row = b * 1024 + qb * 64 + wid * 16 + hi * 4 + i;
      o[(size_t)row * DIM + col] = f2bf(oacc[dj][i] / l_r[i]);
    }
  }
}

extern "C" void kernel_launch(void* const* d_in, const int* in_sizes, int n_in,
                              void* d_out, int out_size, void* d_ws, size_t ws_size,
                              hipStream_t stream)
{
  const float* x      = (const float*)d_in[0];
  const int*   amask  = (const int*)  d_in[1];
  const float* ln1_g  = (const float*)d_in[2];
  const float* ln1_b  = (const float*)d_in[3];
  const float* ln2_g  = (const float*)d_in[4];
  const float* ln2_b  = (const float*)d_in[5];
  const float* w_qkv  = (const float*)d_in[6];
  const float* b_qkv  = (const float*)d_in[7];
  const float* w_proj = (const float*)d_in[8];
  const float* b_proj = (const float*)d_in[9];
  const float* w_fc1  = (const float*)d_in[10];
  const float* b_fc1  = (const float*)d_in[11];
  const float* w_fc2  = (const float*)d_in[12];
  const float* b_fc2  = (const float*)d_in[13];
  float* outp = (float*)d_out;

  char* w = (char*)d_ws;
  auto alloc = [&](size_t bytes){ char* p = w; w += (bytes + 255) & ~(size_t)255; return p; };

  // qkv (18874368 B) + o (6291456 B) region is exactly reused by a1 (25165824 B)
  char* p0 = alloc((size_t)NTOK * 3 * DIM * 2 + (size_t)NTOK * DIM * 2);
  unsigned short* qkv  = (unsigned short*)p0;
  unsigned short* o_bf = (unsigned short*)(p0 + (size_t)NTOK * 3 * DIM * 2);
  unsigned short* a1   = (unsigned short*)p0;                  // aliases qkv+o (dead by then)
  unsigned short* h_bf = (unsigned short*)alloc((size_t)NTOK * DIM * 2);
  unsigned short* h2   = h_bf;                                 // h dead after GEMM1
  float*          x1   = (float*)alloc((size_t)NTOK * DIM * 4);
  unsigned short* wqkvT = (unsigned short*)alloc((size_t)3 * DIM * DIM * 2);
  unsigned short* wprojT= (unsigned short*)alloc((size_t)DIM * DIM * 2);
  unsigned short* wfc1T = (unsigned short*)alloc((size_t)HID * DIM * 2);
  unsigned short* wfc2T = (unsigned short*)alloc((size_t)DIM * HID * 2);

  // weight transposes (fp32 -> bf16, [K][N] -> [N][K])
  transpose_kernel<<<dim3(3 * DIM / 32, DIM / 32), 256, 0, stream>>>(w_qkv,  wqkvT, DIM, 3 * DIM);
  transpose_kernel<<<dim3(DIM / 32, DIM / 32),     256, 0, stream>>>(w_proj, wprojT, DIM, DIM);
  transpose_kernel<<<dim3(HID / 32, DIM / 32),     256, 0, stream>>>(w_fc1,  wfc1T, DIM, HID);
  transpose_kernel<<<dim3(DIM / 32, HID / 32),     256, 0, stream>>>(w_fc2,  wfc2T, HID, DIM);

  // LN1
  ln_kernel<<<NTOK / 4, 256, 0, stream>>>(x, ln1_g, ln1_b, h_bf);
  // QKV: [4096][2304]
  gemm_kernel<128, 0, unsigned short><<<dim3(3 * DIM / 128, NTOK / 128), 256, 0, stream>>>(
      h_bf, wqkvT, b_qkv, nullptr, qkv, NTOK, 3 * DIM, DIM);
  // attention
  attn_kernel<<<dim3(16, 12, 4), 256, 0, stream>>>(qkv, amask, o_bf);
  // proj + residual(x) -> x1 fp32
  gemm_kernel<64, 2, float><<<dim3(DIM / 64, NTOK / 64), 256, 0, stream>>>(
      o_bf, wprojT, b_proj, x, x1, NTOK, DIM, DIM);
  // LN2
  ln_kernel<<<NTOK / 4, 256, 0, stream>>>(x1, ln2_g, ln2_b, h2);
  // FC1 + GELU -> a1 bf16
  gemm_kernel<128, 1, unsigned short><<<dim3(HID / 128, NTOK / 128), 256, 0, stream>>>(
      h2, wfc1T, b_fc1, nullptr, a1, NTOK, HID, DIM);
  // FC2 + residual(x1) -> out fp32
  gemm_kernel<64, 2, float><<<dim3(DIM / 64, NTOK / 64), 256, 0, stream>>>(
      a1, wfc2T, b_fc2, x1, outp, NTOK, DIM, HID);
}

// Round 2
// 213.378 us; speedup vs baseline: 1.0958x; 1.0958x over previous
//
#include <hip/hip_runtime.h>

#define DIM 768
#define NTOK 4096
#define HID 3072

typedef __attribute__((ext_vector_type(8))) short bf16x8;
typedef __attribute__((ext_vector_type(4))) float f32x4;

__device__ inline unsigned short f2bf(float f){
  unsigned u = __float_as_uint(f);
  u += 0x7fff + ((u >> 16) & 1);
  return (unsigned short)(u >> 16);
}
__device__ inline unsigned cvt_pk_bf16(float a, float b){
  unsigned r;
  asm("v_cvt_pk_bf16_f32 %0, %1, %2" : "=v"(r) : "v"(a), "v"(b));
  return r;
}
__device__ inline void gload_lds16(const void* g, void* l){
  __builtin_amdgcn_global_load_lds(
      (const __attribute__((address_space(1))) unsigned int*)g,
      (__attribute__((address_space(3))) unsigned int*)l, 16, 0, 0);
}

// ---------------- LayerNorm: fp32 in -> bf16 out, 1 wave per 768-row ----------------
__global__ __launch_bounds__(256) void ln_kernel(const float* __restrict__ x,
    const float* __restrict__ g, const float* __restrict__ b,
    unsigned short* __restrict__ out)
{
  int row = blockIdx.x * 4 + (threadIdx.x >> 6);
  int lane = threadIdx.x & 63;
  const float* xr = x + (size_t)row * DIM;
  float4 v[3];
  float s = 0.f, s2 = 0.f;
#pragma unroll
  for (int j = 0; j < 3; ++j){
    v[j] = *(const float4*)(xr + j * 256 + lane * 4);
    s  += v[j].x + v[j].y + v[j].z + v[j].w;
    s2 += v[j].x*v[j].x + v[j].y*v[j].y + v[j].z*v[j].z + v[j].w*v[j].w;
  }
#pragma unroll
  for (int m = 1; m < 64; m <<= 1){ s += __shfl_xor(s, m, 64); s2 += __shfl_xor(s2, m, 64); }
  float mu  = s * (1.f / 768.f);
  float var = s2 * (1.f / 768.f) - mu * mu;
  float inv = rsqrtf(var + 1e-5f);
#pragma unroll
  for (int j = 0; j < 3; ++j){
    int c0 = j * 256 + lane * 4;
    float vv[4] = { v[j].x, v[j].y, v[j].z, v[j].w };
    ushort4 o4;
    o4.x = f2bf((vv[0] - mu) * inv * g[c0 + 0] + b[c0 + 0]);
    o4.y = f2bf((vv[1] - mu) * inv * g[c0 + 1] + b[c0 + 1]);
    o4.z = f2bf((vv[2] - mu) * inv * g[c0 + 2] + b[c0 + 2]);
    o4.w = f2bf((vv[3] - mu) * inv * g[c0 + 3] + b[c0 + 3]);
    *(ushort4*)(out + (size_t)row * DIM + c0) = o4;
  }
}

// ---------------- Transpose + bf16 cast: W[K][N] fp32 -> Wt[N][K] bf16 ----------------
__global__ __launch_bounds__(256) void transpose_kernel(const float* __restrict__ W,
    unsigned short* __restrict__ Wt, int K, int N)
{
  __shared__ __align__(16) unsigned short tile[32][33];
  int n0 = blockIdx.x * 32, k0 = blockIdx.y * 32;
  int tx = threadIdx.x & 31, ty = threadIdx.x >> 5;
#pragma unroll
  for (int i = 0; i < 32; i += 8)
    tile[ty + i][tx] = f2bf(W[(size_t)(k0 + ty + i) * N + n0 + tx]);
  __syncthreads();
#pragma unroll
  for (int i = 0; i < 32; i += 8)
    Wt[(size_t)(n0 + ty + i) * K + k0 + tx] = tile[tx][ty + i];
}

// ---------------- pack attention mask into bit-words: pm[b][kt] bit k = mask!=0 ------
__global__ __launch_bounds__(256) void pack_mask_kernel(const int* __restrict__ am,
    unsigned long long* __restrict__ pm)
{
  int lane = threadIdx.x & 63, w = threadIdx.x >> 6, b = blockIdx.x;
  for (int k = w; k < 16; k += 4){
    unsigned long long m = __ballot(am[b * 1024 + k * 64 + lane] != 0);
    if (lane == 0) pm[b * 16 + k] = m;
  }
}

// ---------------- m97-structure MFMA GEMM: C = A[M][K] @ Bt[N][K]^T + bias (+epi) ----
// EPI: 0 bias->bf16, 1 bias+GELU->bf16, 2 bias+resid->fp32, 3 QKV-split writer
template<int BN, int EPI, typename OutT>
__global__ __launch_bounds__(256) void gemm_kernel(
    const unsigned short* __restrict__ A,   // [M][K] bf16
    const unsigned short* __restrict__ Bt,  // [N][K] bf16
    const float* __restrict__ bias,         // [N]
    const float* __restrict__ resid,        // [M][N] (EPI==2)
    OutT* __restrict__ C,                   // [M][N]
    unsigned short* __restrict__ q_out,     // EPI==3
    unsigned short* __restrict__ k_out,
    unsigned short* __restrict__ v_out,
    int M, int N, int K)
{
  constexpr int BM = 128, BK = 32;
  constexpr int WN = BN / 2, NI = WN / 16;      // MI = 4
  constexpr int ACH = BM * BK / 8;              // 512 16B chunks
  constexpr int BCH = BN * BK / 8;              // 512 or 256
  constexpr int NCALL = (ACH + BCH) / 256;
  __shared__ __align__(16) unsigned short As[BM * BK];
  __shared__ __align__(16) unsigned short Bs[BN * BK];
  const int t = threadIdx.x, lane = t & 63, wid = t >> 6;
  const int lo = lane & 15, hi = lane >> 4;
  const int wr = wid >> 1, wc = wid & 1;
  const int bm = blockIdx.y * BM, bn = blockIdx.x * BN;

  f32x4 acc[4][NI];
#pragma unroll
  for (int i = 0; i < 4; ++i)
#pragma unroll
    for (int j = 0; j < NI; ++j) acc[i][j] = (f32x4){0.f, 0.f, 0.f, 0.f};

  for (int k0 = 0; k0 < K; k0 += BK){
    __syncthreads();          // previous iteration's frag reads done
#pragma unroll
    for (int u = 0; u < NCALL; ++u){
      int c = u * 256 + t;
      if (c < ACH){
        int r = c >> 2, cq = c & 3;
        gload_lds16(A + (size_t)(bm + r) * K + k0 + cq * 8, As + c * 8);
      } else {
        int c2 = c - ACH, r = c2 >> 2, cq = c2 & 3;
        gload_lds16(Bt + (size_t)(bn + r) * K + k0 + cq * 8, Bs + c2 * 8);
      }
    }
    __syncthreads();          // compiler drains vmcnt before s_barrier
    bf16x8 af[4], bfr[NI];
#pragma unroll
    for (int i = 0; i < 4; ++i)  af[i]  = *(const bf16x8*)&As[(wr * 64 + i * 16 + lo) * BK + hi * 8];
#pragma unroll
    for (int j = 0; j < NI; ++j) bfr[j] = *(const bf16x8*)&Bs[(wc * WN + j * 16 + lo) * BK + hi * 8];
#pragma unroll
    for (int i = 0; i < 4; ++i)
#pragma unroll
      for (int j = 0; j < NI; ++j)
        acc[i][j] = __builtin_amdgcn_mfma_f32_16x16x32_bf16(af[i], bfr[j], acc[i][j], 0, 0, 0);
  }

  // epilogue: C/D layout col = lane&15, row = (lane>>4)*4 + r
#pragma unroll
  for (int i = 0; i < 4; ++i){
#pragma unroll
    for (int j = 0; j < NI; ++j){
      int col = bn + wc * WN + j * 16 + lo;
      float bcol = bias[col];
      if constexpr (EPI == 3){
        int hh = (col % 768) >> 6, d = col & 63;
        int part = col / 768;
        int row0 = bm + wr * 64 + i * 16 + hi * 4;
        int bb = row0 >> 10, n0 = row0 & 1023;
        size_t bh = (size_t)bb * 12 + hh;
        float v0 = acc[i][j][0] + bcol, v1 = acc[i][j][1] + bcol;
        float v2 = acc[i][j][2] + bcol, v3 = acc[i][j][3] + bcol;
        if (part == 0){
          q_out[(bh * 1024 + n0 + 0) * 64 + d] = f2bf(v0);
          q_out[(bh * 1024 + n0 + 1) * 64 + d] = f2bf(v1);
          q_out[(bh * 1024 + n0 + 2) * 64 + d] = f2bf(v2);
          q_out[(bh * 1024 + n0 + 3) * 64 + d] = f2bf(v3);
        } else if (part == 1){
          k_out[(bh * 1024 + n0 + 0) * 64 + d] = f2bf(v0);
          k_out[(bh * 1024 + n0 + 1) * 64 + d] = f2bf(v1);
          k_out[(bh * 1024 + n0 + 2) * 64 + d] = f2bf(v2);
          k_out[(bh * 1024 + n0 + 3) * 64 + d] = f2bf(v3);
        } else {
          unsigned w0 = cvt_pk_bf16(v0, v1), w1 = cvt_pk_bf16(v2, v3);
          *(uint2*)&v_out[bh * 65536 + (size_t)d * 1024 + n0] = make_uint2(w0, w1);
        }
      } else {
#pragma unroll
        for (int r = 0; r < 4; ++r){
          int row = bm + wr * 64 + i * 16 + hi * 4 + r;
          float v = acc[i][j][r] + bcol;
          if constexpr (EPI == 1) v = 0.5f * v * (1.f + erff(v * 0.70710678118f));
          if constexpr (EPI == 2) v += resid[(size_t)row * N + col];
          if constexpr (sizeof(OutT) == 2) C[(size_t)row * N + col] = f2bf(v);
          else                             C[(size_t)row * N + col] = v;
        }
      }
    }
  }
}

// ---------------- Flash attention, swapped-operand (S^T = K·Q^T), fixed-max softmax --
// grid (qb=16, h=12, b=4), 4 waves; wave w owns q-rows qb*64 + w*16 + (lane&15)
__global__ __launch_bounds__(256) void attn_kernel(
    const unsigned short* __restrict__ Qs,   // [b*h][1024][64]
    const unsigned short* __restrict__ Ks,   // [b*h][1024][64]
    const unsigned short* __restrict__ Vts,  // [b*h][64][1024]  (V transposed)
    const unsigned long long* __restrict__ pm,
    unsigned short* __restrict__ o)          // [token][768]
{
  constexpr int LD = 72;
  __shared__ __align__(16) unsigned short Kl[64 * LD];
  __shared__ __align__(16) unsigned short Vt[64 * LD];
  __shared__ __align__(16) unsigned short Pl[4][16 * LD];
  const int qb = blockIdx.x, h = blockIdx.y, b = blockIdx.z;
  const int t = threadIdx.x, wid = t >> 6, lane = t & 63;
  const int lo = lane & 15, hi = lane >> 4;
  const size_t bh = (size_t)b * 12 + h;

  // Q fragments (B-operand): lane (lo,hi) holds Q[q=lo][d = kk*32 + hi*8 .. +7]
  const unsigned short* Qg = Qs + (bh * 1024 + qb * 64 + wid * 16 + lo) * 64;
  bf16x8 qf0 = *(const bf16x8*)(Qg + hi * 8);
  bf16x8 qf1 = *(const bf16x8*)(Qg + 32 + hi * 8);

  f32x4 oacc[4];
#pragma unroll
  for (int dj = 0; dj < 4; ++dj) oacc[dj] = (f32x4){0.f, 0.f, 0.f, 0.f};
  float l_part = 0.f;

  const int srow = t >> 2, scol = (t & 3) * 16;
  const unsigned short* Kg = Ks  + bh * 65536;
  const unsigned short* Vg = Vts + bh * 65536;
  unsigned short* pw = &Pl[wid][0];

  for (int kt = 0; kt < 16; ++kt){
    __syncthreads();
    const unsigned short* kg = Kg + (kt * 64 + srow) * 64 + scol;
    *(bf16x8*)&Kl[srow * LD + scol]     = *(const bf16x8*)kg;
    *(bf16x8*)&Kl[srow * LD + scol + 8] = *(const bf16x8*)(kg + 8);
    const unsigned short* vg = Vg + srow * 1024 + kt * 64 + scol;
    *(bf16x8*)&Vt[srow * LD + scol]     = *(const bf16x8*)vg;
    *(bf16x8*)&Vt[srow * LD + scol + 8] = *(const bf16x8*)(vg + 8);
    __syncthreads();

    // S^T = K · Q^T : lane (lo,hi) gets S[q=lo][key = nj*16 + hi*4 + r]
    f32x4 s[4];
#pragma unroll
    for (int nj = 0; nj < 4; ++nj) s[nj] = (f32x4){0.f, 0.f, 0.f, 0.f};
#pragma unroll
    for (int kk = 0; kk < 2; ++kk){
      bf16x8 q = kk ? qf1 : qf0;
#pragma unroll
      for (int nj = 0; nj < 4; ++nj){
        bf16x8 kf = *(const bf16x8*)&Kl[(nj * 16 + lo) * LD + kk * 32 + hi * 8];
        s[nj] = __builtin_amdgcn_mfma_f32_16x16x32_bf16(kf, q, s[nj], 0, 0, 0);
      }
    }

    // fixed-shift softmax numerator + mask, fully lane-local
    unsigned long long w = pm[b * 16 + kt] >> (hi * 4);
#pragma unroll
    for (int nj = 0; nj < 4; ++nj){
      float p[4];
#pragma unroll
      for (int r = 0; r < 4; ++r){
        float e = __expf(fmaf(s[nj][r], 0.125f, -16.0f));
        e = ((unsigned)(w >> (nj * 16 + r)) & 1u) ? e : 0.0f;
        l_part += e;
        p[r] = e;
      }
      unsigned w0 = cvt_pk_bf16(p[0], p[1]);
      unsigned w1 = cvt_pk_bf16(p[2], p[3]);
      *(uint2*)&pw[lo * LD + nj * 16 + hi * 4] = make_uint2(w0, w1);
    }
    asm volatile("" ::: "memory");   // keep ds_writes before pf reads (in-wave, in-order LDS)
    bf16x8 pf0 = *(const bf16x8*)&pw[lo * LD + hi * 8];
    bf16x8 pf1 = *(const bf16x8*)&pw[lo * LD + 32 + hi * 8];
    // O^T += V^T · P^T : lane (lo,hi) gets O^T[d = dj*16 + hi*4 + r][q = lo]
#pragma unroll
    for (int kk = 0; kk < 2; ++kk){
      bf16x8 pf = kk ? pf1 : pf0;
#pragma unroll
      for (int dj = 0; dj < 4; ++dj){
        bf16x8 vf = *(const bf16x8*)&Vt[(dj * 16 + lo) * LD + kk * 32 + hi * 8];
        oacc[dj] = __builtin_amdgcn_mfma_f32_16x16x32_bf16(vf, pf, oacc[dj], 0, 0, 0);
      }
    }
  }

  float l = l_part;
  l += __shfl_xor(l, 16, 64);
  l += __shfl_xor(l, 32, 64);
  float inv = 1.0f / l;
  size_t orow = (size_t)b * 1024 + qb * 64 + wid * 16 + lo;
#pragma unroll
  for (int dj = 0; dj < 4; ++dj){
    unsigned w0 = (unsigned)f2bf(oacc[dj][0] * inv) | ((unsigned)f2bf(oacc[dj][1] * inv) << 16);
    unsigned w1 = (unsigned)f2bf(oacc[dj][2] * inv) | ((unsigned)f2bf(oacc[dj][3] * inv) << 16);
    *(uint2*)&o[orow * DIM + h * 64 + dj * 16 + hi * 4] = make_uint2(w0, w1);
  }
}

extern "C" void kernel_launch(void* const* d_in, const int* in_sizes, int n_in,
                              void* d_out, int out_size, void* d_ws, size_t ws_size,
                              hipStream_t stream)
{
  const float* x      = (const float*)d_in[0];
  const int*   amask  = (const int*)  d_in[1];
  const float* ln1_g  = (const float*)d_in[2];
  const float* ln1_b  = (const float*)d_in[3];
  const float* ln2_g  = (const float*)d_in[4];
  const float* ln2_b  = (const float*)d_in[5];
  const float* w_qkv  = (const float*)d_in[6];
  const float* b_qkv  = (const float*)d_in[7];
  const float* w_proj = (const float*)d_in[8];
  const float* b_proj = (const float*)d_in[9];
  const float* w_fc1  = (const float*)d_in[10];
  const float* b_fc1  = (const float*)d_in[11];
  const float* w_fc2  = (const float*)d_in[12];
  const float* b_fc2  = (const float*)d_in[13];
  float* outp = (float*)d_out;

  char* w = (char*)d_ws;
  auto alloc = [&](size_t bytes){ char* p = w; w += (bytes + 255) & ~(size_t)255; return p; };

  // Qs+Ks+Vts+o_bf (4 x 6291456 B) exactly reused by a1 (25165824 B, dead-by-then)
  char* p0 = alloc((size_t)4 * 6291456);
  unsigned short* Qs   = (unsigned short*)p0;
  unsigned short* Ks   = (unsigned short*)(p0 + 6291456);
  unsigned short* Vts  = (unsigned short*)(p0 + 2 * 6291456);
  unsigned short* o_bf = (unsigned short*)(p0 + 3 * 6291456);
  unsigned short* a1   = (unsigned short*)p0;
  unsigned short* h_bf = (unsigned short*)alloc((size_t)NTOK * DIM * 2);
  unsigned short* h2   = h_bf;
  float*          x1   = (float*)alloc((size_t)NTOK * DIM * 4);
  unsigned short* wqkvT = (unsigned short*)alloc((size_t)3 * DIM * DIM * 2);
  unsigned short* wprojT= (unsigned short*)alloc((size_t)DIM * DIM * 2);
  unsigned short* wfc1T = (unsigned short*)alloc((size_t)HID * DIM * 2);
  unsigned short* wfc2T = (unsigned short*)alloc((size_t)DIM * HID * 2);
  unsigned long long* pmask = (unsigned long long*)alloc(4 * 16 * 8);

  transpose_kernel<<<dim3(3 * DIM / 32, DIM / 32), 256, 0, stream>>>(w_qkv,  wqkvT, DIM, 3 * DIM);
  transpose_kernel<<<dim3(DIM / 32, DIM / 32),     256, 0, stream>>>(w_proj, wprojT, DIM, DIM);
  transpose_kernel<<<dim3(HID / 32, DIM / 32),     256, 0, stream>>>(w_fc1,  wfc1T, DIM, HID);
  transpose_kernel<<<dim3(DIM / 32, HID / 32),     256, 0, stream>>>(w_fc2,  wfc2T, HID, DIM);
  pack_mask_kernel<<<4, 256, 0, stream>>>(amask, pmask);

  ln_kernel<<<NTOK / 4, 256, 0, stream>>>(x, ln1_g, ln1_b, h_bf);
  // QKV GEMM with split epilogue -> Qs, Ks, Vts
  gemm_kernel<128, 3, unsigned short><<<dim3(2304 / 128, NTOK / 128), 256, 0, stream>>>(
      h_bf, wqkvT, b_qkv, nullptr, (unsigned short*)nullptr, Qs, Ks, Vts, NTOK, 2304, DIM);
  attn_kernel<<<dim3(16, 12, 4), 256, 0, stream>>>(Qs, Ks, Vts, pmask, o_bf);
  // proj + residual(x) -> x1 fp32
  gemm_kernel<64, 2, float><<<dim3(DIM / 64, NTOK / 128), 256, 0, stream>>>(
      o_bf, wprojT, b_proj, x, x1, nullptr, nullptr, nullptr, NTOK, DIM, DIM);
  ln_kernel<<<NTOK / 4, 256, 0, stream>>>(x1, ln2_g, ln2_b, h2);
  // FC1 + GELU -> a1 bf16
  gemm_kernel<128, 1, unsigned short><<<dim3(HID / 128, NTOK / 128), 256, 0, stream>>>(
      h2, wfc1T, b_fc1, nullptr, a1, nullptr, nullptr, nullptr, NTOK, HID, DIM);
  // FC2 + residual(x1) -> out fp32
  gemm_kernel<64, 2, float><<<dim3(DIM / 64, NTOK / 128), 256, 0, stream>>>(
      a1, wfc2T, b_fc2, x1, outp, nullptr, nullptr, nullptr, NTOK, DIM, HID);
}

// Round 3
// 192.012 us; speedup vs baseline: 1.2177x; 1.1113x over previous
//
#include <hip/hip_runtime.h>

#define DIM 768
#define NTOK 4096
#define HID 3072

typedef __attribute__((ext_vector_type(8))) short bf16x8;
typedef __attribute__((ext_vector_type(4))) float f32x4;

__device__ inline unsigned short f2bf(float f){
  unsigned u = __float_as_uint(f);
  u += 0x7fff + ((u >> 16) & 1);
  return (unsigned short)(u >> 16);
}
__device__ inline unsigned cvt_pk_bf16(float a, float b){
  unsigned r;
  asm("v_cvt_pk_bf16_f32 %0, %1, %2" : "=v"(r) : "v"(a), "v"(b));
  return r;
}
__device__ inline void gload_lds16(const void* g, void* l){
  __builtin_amdgcn_global_load_lds(
      (const __attribute__((address_space(1))) unsigned int*)g,
      (__attribute__((address_space(3))) unsigned int*)l, 16, 0, 0);
}

// ---------------- LayerNorm: fp32 in -> bf16 out, 1 wave per 768-row ----------------
__global__ __launch_bounds__(256) void ln_kernel(const float* __restrict__ x,
    const float* __restrict__ g, const float* __restrict__ b,
    unsigned short* __restrict__ out)
{
  int row = blockIdx.x * 4 + (threadIdx.x >> 6);
  int lane = threadIdx.x & 63;
  const float* xr = x + (size_t)row * DIM;
  float4 v[3];
  float s = 0.f, s2 = 0.f;
#pragma unroll
  for (int j = 0; j < 3; ++j){
    v[j] = *(const float4*)(xr + j * 256 + lane * 4);
    s  += v[j].x + v[j].y + v[j].z + v[j].w;
    s2 += v[j].x*v[j].x + v[j].y*v[j].y + v[j].z*v[j].z + v[j].w*v[j].w;
  }
#pragma unroll
  for (int m = 1; m < 64; m <<= 1){ s += __shfl_xor(s, m, 64); s2 += __shfl_xor(s2, m, 64); }
  float mu  = s * (1.f / 768.f);
  float var = s2 * (1.f / 768.f) - mu * mu;
  float inv = rsqrtf(var + 1e-5f);
#pragma unroll
  for (int j = 0; j < 3; ++j){
    int c0 = j * 256 + lane * 4;
    float vv[4] = { v[j].x, v[j].y, v[j].z, v[j].w };
    ushort4 o4;
    o4.x = f2bf((vv[0] - mu) * inv * g[c0 + 0] + b[c0 + 0]);
    o4.y = f2bf((vv[1] - mu) * inv * g[c0 + 1] + b[c0 + 1]);
    o4.z = f2bf((vv[2] - mu) * inv * g[c0 + 2] + b[c0 + 2]);
    o4.w = f2bf((vv[3] - mu) * inv * g[c0 + 3] + b[c0 + 3]);
    *(ushort4*)(out + (size_t)row * DIM + c0) = o4;
  }
}

// ------- fused weight transposes: 4 weights, W[K][N] fp32 -> Wt[N][K] bf16 ----------
// tile ranges: qkv [0,1728) 72x24 | proj [1728,2304) 24x24 | fc1 [2304,4608) 96x24
//              fc2 [4608,6912) 24x96
__global__ __launch_bounds__(256) void transpose4_kernel(
    const float* __restrict__ w_qkv, const float* __restrict__ w_proj,
    const float* __restrict__ w_fc1, const float* __restrict__ w_fc2,
    unsigned short* __restrict__ tq, unsigned short* __restrict__ tp,
    unsigned short* __restrict__ t1, unsigned short* __restrict__ t2)
{
  __shared__ __align__(16) unsigned short tile[32][33];
  int id = blockIdx.x;
  const float* W; unsigned short* Wt; int K, N, tx_n;
  if (id < 1728)      { W = w_qkv;  Wt = tq; K = 768;  N = 2304; tx_n = 72; }
  else if (id < 2304) { W = w_proj; Wt = tp; K = 768;  N = 768;  tx_n = 24; id -= 1728; }
  else if (id < 4608) { W = w_fc1;  Wt = t1; K = 768;  N = 3072; tx_n = 96; id -= 2304; }
  else                { W = w_fc2;  Wt = t2; K = 3072; N = 768;  tx_n = 24; id -= 4608; }
  int n0 = (id % tx_n) * 32, k0 = (id / tx_n) * 32;
  int tx = threadIdx.x & 31, ty = threadIdx.x >> 5;
#pragma unroll
  for (int i = 0; i < 32; i += 8)
    tile[ty + i][tx] = f2bf(W[(size_t)(k0 + ty + i) * N + n0 + tx]);
  __syncthreads();
#pragma unroll
  for (int i = 0; i < 32; i += 8)
    Wt[(size_t)(n0 + ty + i) * K + k0 + tx] = tile[tx][ty + i];
}

// ---------------- pack attention mask into bit-words: pm[b][kt] bit k = mask!=0 ------
__global__ __launch_bounds__(256) void pack_mask_kernel(const int* __restrict__ am,
    unsigned long long* __restrict__ pm)
{
  int lane = threadIdx.x & 63, w = threadIdx.x >> 6, b = blockIdx.x;
  for (int k = w; k < 16; k += 4){
    unsigned long long m = __ballot(am[b * 1024 + k * 64 + lane] != 0);
    if (lane == 0) pm[b * 16 + k] = m;
  }
}

// ------- MFMA GEMM, 2-phase double-buffered + XCD swizzle -------
// EPI: 0 bias->bf16, 1 bias+GELU->bf16, 2 bias+resid->fp32, 3 QKV-split writer
template<int BN, int EPI, typename OutT>
__global__ __launch_bounds__(256) void gemm_kernel(
    const unsigned short* __restrict__ A,   // [M][K] bf16
    const unsigned short* __restrict__ Bt,  // [N][K] bf16
    const float* __restrict__ bias,         // [N]
    const float* __restrict__ resid,        // [M][N] (EPI==2)
    OutT* __restrict__ C,                   // [M][N]
    unsigned short* __restrict__ q_out,     // EPI==3
    unsigned short* __restrict__ k_out,
    unsigned short* __restrict__ v_out,
    int M, int N, int K)
{
  constexpr int BM = 128, BK = 32;
  constexpr int WN = BN / 2, NI = WN / 16;
  constexpr int ACH = BM * BK / 8;              // 512 16B chunks
  constexpr int BCH = BN * BK / 8;              // 512 or 256
  constexpr int NC = (ACH + BCH) / 256;
  __shared__ __align__(16) unsigned short As[2][BM * BK];
  __shared__ __align__(16) unsigned short Bs[2][BN * BK];
  const int t = threadIdx.x, lane = t & 63, wid = t >> 6;
  const int lo = lane & 15, hi = lane >> 4;
  const int wr = wid >> 1, wc = wid & 1;

  // bijective XCD swizzle (nwg % 8 == 0 for all our grids), row-major chunks:
  // each XCD runs contiguous columns of the same A row-panel -> L2 reuse
  const int gx = gridDim.x;
  const int nwg = gx * gridDim.y;
  const int lin = blockIdx.y * gx + blockIdx.x;
  const int swz = (lin & 7) * (nwg >> 3) + (lin >> 3);
  const int bm = (swz / gx) * BM, bn = (swz % gx) * BN;

  auto stage = [&](int buf, int k0){
#pragma unroll
    for (int u = 0; u < NC; ++u){
      int c = u * 256 + t;
      if (c < ACH){
        gload_lds16(A + (size_t)(bm + (c >> 2)) * K + k0 + (c & 3) * 8, &As[buf][c * 8]);
      } else {
        int c2 = c - ACH;
        gload_lds16(Bt + (size_t)(bn + (c2 >> 2)) * K + k0 + (c2 & 3) * 8, &Bs[buf][c2 * 8]);
      }
    }
  };

  f32x4 acc[4][NI];
#pragma unroll
  for (int i = 0; i < 4; ++i)
#pragma unroll
    for (int j = 0; j < NI; ++j) acc[i][j] = (f32x4){0.f, 0.f, 0.f, 0.f};

  stage(0, 0);
  __syncthreads();                 // drains vmcnt(0): buffer 0 ready
  const int NIT = K / BK;
  int cur = 0;
  for (int it = 0; it < NIT; ++it){
    if (it + 1 < NIT) stage(cur ^ 1, (it + 1) * BK);   // loads fly during compute
    bf16x8 af[4], bfr[NI];
#pragma unroll
    for (int i = 0; i < 4; ++i)  af[i]  = *(const bf16x8*)&As[cur][(wr * 64 + i * 16 + lo) * BK + hi * 8];
#pragma unroll
    for (int j = 0; j < NI; ++j) bfr[j] = *(const bf16x8*)&Bs[cur][(wc * WN + j * 16 + lo) * BK + hi * 8];
#pragma unroll
    for (int i = 0; i < 4; ++i)
#pragma unroll
      for (int j = 0; j < NI; ++j)
        acc[i][j] = __builtin_amdgcn_mfma_f32_16x16x32_bf16(af[i], bfr[j], acc[i][j], 0, 0, 0);
    __syncthreads();               // next buffer staged; all reads of cur done
    cur ^= 1;
  }

  // epilogue: C/D layout col = lane&15, row = (lane>>4)*4 + r
#pragma unroll
  for (int i = 0; i < 4; ++i){
#pragma unroll
    for (int j = 0; j < NI; ++j){
      int col = bn + wc * WN + j * 16 + lo;
      float bcol = bias[col];
      if constexpr (EPI == 3){
        int hh = (col % 768) >> 6, d = col & 63;
        int part = col / 768;
        int row0 = bm + wr * 64 + i * 16 + hi * 4;
        int bb = row0 >> 10, n0 = row0 & 1023;
        size_t bh = (size_t)bb * 12 + hh;
        float v0 = acc[i][j][0] + bcol, v1 = acc[i][j][1] + bcol;
        float v2 = acc[i][j][2] + bcol, v3 = acc[i][j][3] + bcol;
        if (part == 0){
          q_out[(bh * 1024 + n0 + 0) * 64 + d] = f2bf(v0);
          q_out[(bh * 1024 + n0 + 1) * 64 + d] = f2bf(v1);
          q_out[(bh * 1024 + n0 + 2) * 64 + d] = f2bf(v2);
          q_out[(bh * 1024 + n0 + 3) * 64 + d] = f2bf(v3);
        } else if (part == 1){
          k_out[(bh * 1024 + n0 + 0) * 64 + d] = f2bf(v0);
          k_out[(bh * 1024 + n0 + 1) * 64 + d] = f2bf(v1);
          k_out[(bh * 1024 + n0 + 2) * 64 + d] = f2bf(v2);
          k_out[(bh * 1024 + n0 + 3) * 64 + d] = f2bf(v3);
        } else {
          unsigned w0 = cvt_pk_bf16(v0, v1), w1 = cvt_pk_bf16(v2, v3);
          *(uint2*)&v_out[bh * 65536 + (size_t)d * 1024 + n0] = make_uint2(w0, w1);
        }
      } else {
#pragma unroll
        for (int r = 0; r < 4; ++r){
          int row = bm + wr * 64 + i * 16 + hi * 4 + r;
          float v = acc[i][j][r] + bcol;
          if constexpr (EPI == 1) v = 0.5f * v * (1.f + erff(v * 0.70710678118f));
          if constexpr (EPI == 2) v += resid[(size_t)row * N + col];
          if constexpr (sizeof(OutT) == 2) C[(size_t)row * N + col] = f2bf(v);
          else                             C[(size_t)row * N + col] = v;
        }
      }
    }
  }
}

// ---------------- Flash attention, swapped-operand (S^T = K·Q^T), fixed-max softmax --
__global__ __launch_bounds__(256) void attn_kernel(
    const unsigned short* __restrict__ Qs,   // [b*h][1024][64]
    const unsigned short* __restrict__ Ks,   // [b*h][1024][64]
    const unsigned short* __restrict__ Vts,  // [b*h][64][1024]  (V transposed)
    const unsigned long long* __restrict__ pm,
    unsigned short* __restrict__ o)          // [token][768]
{
  constexpr int LD = 72;
  __shared__ __align__(16) unsigned short Kl[64 * LD];
  __shared__ __align__(16) unsigned short Vt[64 * LD];
  __shared__ __align__(16) unsigned short Pl[4][16 * LD];
  const int qb = blockIdx.x, h = blockIdx.y, b = blockIdx.z;
  const int t = threadIdx.x, wid = t >> 6, lane = t & 63;
  const int lo = lane & 15, hi = lane >> 4;
  const size_t bh = (size_t)b * 12 + h;

  const unsigned short* Qg = Qs + (bh * 1024 + qb * 64 + wid * 16 + lo) * 64;
  bf16x8 qf0 = *(const bf16x8*)(Qg + hi * 8);
  bf16x8 qf1 = *(const bf16x8*)(Qg + 32 + hi * 8);

  f32x4 oacc[4];
#pragma unroll
  for (int dj = 0; dj < 4; ++dj) oacc[dj] = (f32x4){0.f, 0.f, 0.f, 0.f};
  float l_part = 0.f;

  const int srow = t >> 2, scol = (t & 3) * 16;
  const unsigned short* Kg = Ks  + bh * 65536;
  const unsigned short* Vg = Vts + bh * 65536;
  unsigned short* pw = &Pl[wid][0];

  for (int kt = 0; kt < 16; ++kt){
    __syncthreads();
    const unsigned short* kg = Kg + (kt * 64 + srow) * 64 + scol;
    *(bf16x8*)&Kl[srow * LD + scol]     = *(const bf16x8*)kg;
    *(bf16x8*)&Kl[srow * LD + scol + 8] = *(const bf16x8*)(kg + 8);
    const unsigned short* vg = Vg + srow * 1024 + kt * 64 + scol;
    *(bf16x8*)&Vt[srow * LD + scol]     = *(const bf16x8*)vg;
    *(bf16x8*)&Vt[srow * LD + scol + 8] = *(const bf16x8*)(vg + 8);
    __syncthreads();

    f32x4 s[4];
#pragma unroll
    for (int nj = 0; nj < 4; ++nj) s[nj] = (f32x4){0.f, 0.f, 0.f, 0.f};
#pragma unroll
    for (int kk = 0; kk < 2; ++kk){
      bf16x8 q = kk ? qf1 : qf0;
#pragma unroll
      for (int nj = 0; nj < 4; ++nj){
        bf16x8 kf = *(const bf16x8*)&Kl[(nj * 16 + lo) * LD + kk * 32 + hi * 8];
        s[nj] = __builtin_amdgcn_mfma_f32_16x16x32_bf16(kf, q, s[nj], 0, 0, 0);
      }
    }

    unsigned long long w = pm[b * 16 + kt] >> (hi * 4);
#pragma unroll
    for (int nj = 0; nj < 4; ++nj){
      float p[4];
#pragma unroll
      for (int r = 0; r < 4; ++r){
        float e = __expf(fmaf(s[nj][r], 0.125f, -16.0f));
        e = ((unsigned)(w >> (nj * 16 + r)) & 1u) ? e : 0.0f;
        l_part += e;
        p[r] = e;
      }
      unsigned w0 = cvt_pk_bf16(p[0], p[1]);
      unsigned w1 = cvt_pk_bf16(p[2], p[3]);
      *(uint2*)&pw[lo * LD + nj * 16 + hi * 4] = make_uint2(w0, w1);
    }
    asm volatile("" ::: "memory");
    bf16x8 pf0 = *(const bf16x8*)&pw[lo * LD + hi * 8];
    bf16x8 pf1 = *(const bf16x8*)&pw[lo * LD + 32 + hi * 8];
#pragma unroll
    for (int kk = 0; kk < 2; ++kk){
      bf16x8 pf = kk ? pf1 : pf0;
#pragma unroll
      for (int dj = 0; dj < 4; ++dj){
        bf16x8 vf = *(const bf16x8*)&Vt[(dj * 16 + lo) * LD + kk * 32 + hi * 8];
        oacc[dj] = __builtin_amdgcn_mfma_f32_16x16x32_bf16(vf, pf, oacc[dj], 0, 0, 0);
      }
    }
  }

  float l = l_part;
  l += __shfl_xor(l, 16, 64);
  l += __shfl_xor(l, 32, 64);
  float inv = 1.0f / l;
  size_t orow = (size_t)b * 1024 + qb * 64 + wid * 16 + lo;
#pragma unroll
  for (int dj = 0; dj < 4; ++dj){
    unsigned w0 = (unsigned)f2bf(oacc[dj][0] * inv) | ((unsigned)f2bf(oacc[dj][1] * inv) << 16);
    unsigned w1 = (unsigned)f2bf(oacc[dj][2] * inv) | ((unsigned)f2bf(oacc[dj][3] * inv) << 16);
    *(uint2*)&o[orow * DIM + h * 64 + dj * 16 + hi * 4] = make_uint2(w0, w1);
  }
}

extern "C" void kernel_launch(void* const* d_in, const int* in_sizes, int n_in,
                              void* d_out, int out_size, void* d_ws, size_t ws_size,
                              hipStream_t stream)
{
  const float* x      = (const float*)d_in[0];
  const int*   amask  = (const int*)  d_in[1];
  const float* ln1_g  = (const float*)d_in[2];
  const float* ln1_b  = (const float*)d_in[3];
  const float* ln2_g  = (const float*)d_in[4];
  const float* ln2_b  = (const float*)d_in[5];
  const float* w_qkv  = (const float*)d_in[6];
  const float* b_qkv  = (const float*)d_in[7];
  const float* w_proj = (const float*)d_in[8];
  const float* b_proj = (const float*)d_in[9];
  const float* w_fc1  = (const float*)d_in[10];
  const float* b_fc1  = (const float*)d_in[11];
  const float* w_fc2  = (const float*)d_in[12];
  const float* b_fc2  = (const float*)d_in[13];
  float* outp = (float*)d_out;

  char* w = (char*)d_ws;
  auto alloc = [&](size_t bytes){ char* p = w; w += (bytes + 255) & ~(size_t)255; return p; };

  char* p0 = alloc((size_t)4 * 6291456);
  unsigned short* Qs   = (unsigned short*)p0;
  unsigned short* Ks   = (unsigned short*)(p0 + 6291456);
  unsigned short* Vts  = (unsigned short*)(p0 + 2 * 6291456);
  unsigned short* o_bf = (unsigned short*)(p0 + 3 * 6291456);
  unsigned short* a1   = (unsigned short*)p0;
  unsigned short* h_bf = (unsigned short*)alloc((size_t)NTOK * DIM * 2);
  unsigned short* h2   = h_bf;
  float*          x1   = (float*)alloc((size_t)NTOK * DIM * 4);
  unsigned short* wqkvT = (unsigned short*)alloc((size_t)3 * DIM * DIM * 2);
  unsigned short* wprojT= (unsigned short*)alloc((size_t)DIM * DIM * 2);
  unsigned short* wfc1T = (unsigned short*)alloc((size_t)HID * DIM * 2);
  unsigned short* wfc2T = (unsigned short*)alloc((size_t)DIM * HID * 2);
  unsigned long long* pmask = (unsigned long long*)alloc(4 * 16 * 8);

  transpose4_kernel<<<6912, 256, 0, stream>>>(w_qkv, w_proj, w_fc1, w_fc2,
                                              wqkvT, wprojT, wfc1T, wfc2T);
  pack_mask_kernel<<<4, 256, 0, stream>>>(amask, pmask);

  ln_kernel<<<NTOK / 4, 256, 0, stream>>>(x, ln1_g, ln1_b, h_bf);
  gemm_kernel<128, 3, unsigned short><<<dim3(2304 / 128, NTOK / 128), 256, 0, stream>>>(
      h_bf, wqkvT, b_qkv, nullptr, (unsigned short*)nullptr, Qs, Ks, Vts, NTOK, 2304, DIM);
  attn_kernel<<<dim3(16, 12, 4), 256, 0, stream>>>(Qs, Ks, Vts, pmask, o_bf);
  gemm_kernel<64, 2, float><<<dim3(DIM / 64, NTOK / 128), 256, 0, stream>>>(
      o_bf, wprojT, b_proj, x, x1, nullptr, nullptr, nullptr, NTOK, DIM, DIM);
  ln_kernel<<<NTOK / 4, 256, 0, stream>>>(x1, ln2_g, ln2_b, h2);
  gemm_kernel<128, 1, unsigned short><<<dim3(HID / 128, NTOK / 128), 256, 0, stream>>>(
      h2, wfc1T, b_fc1, nullptr, a1, nullptr, nullptr, nullptr, NTOK, HID, DIM);
  gemm_kernel<64, 2, float><<<dim3(DIM / 64, NTOK / 128), 256, 0, stream>>>(
      a1, wfc2T, b_fc2, x1, outp, nullptr, nullptr, nullptr, NTOK, DIM, HID);
}

// Round 4
// 188.305 us; speedup vs baseline: 1.2417x; 1.0197x over previous
//
#include <hip/hip_runtime.h>

#define DIM 768
#define NTOK 4096
#define HID 3072

typedef __attribute__((ext_vector_type(8))) short bf16x8;
typedef __attribute__((ext_vector_type(4))) float f32x4;

__device__ inline unsigned short f2bf(float f){
  unsigned u = __float_as_uint(f);
  u += 0x7fff + ((u >> 16) & 1);
  return (unsigned short)(u >> 16);
}
__device__ inline unsigned cvt_pk_bf16(float a, float b){
  unsigned r;
  asm("v_cvt_pk_bf16_f32 %0, %1, %2" : "=v"(r) : "v"(a), "v"(b));
  return r;
}
__device__ inline void gload_lds16(const void* g, void* l){
  __builtin_amdgcn_global_load_lds(
      (const __attribute__((address_space(1))) unsigned int*)g,
      (__attribute__((address_space(3))) unsigned int*)l, 16, 0, 0);
}
template<int N> __device__ inline void wait_vmcnt(){
  if constexpr (N == 0) asm volatile("s_waitcnt vmcnt(0)" ::: "memory");
  else if constexpr (N == 2) asm volatile("s_waitcnt vmcnt(2)" ::: "memory");
  else if constexpr (N == 3) asm volatile("s_waitcnt vmcnt(3)" ::: "memory");
  else if constexpr (N == 4) asm volatile("s_waitcnt vmcnt(4)" ::: "memory");
  else static_assert(N == 0, "unsupported vmcnt");
}

// ---------------- LayerNorm: fp32 in -> bf16 out, 1 wave per 768-row ----------------
__global__ __launch_bounds__(256) void ln_kernel(const float* __restrict__ x,
    const float* __restrict__ g, const float* __restrict__ b,
    unsigned short* __restrict__ out)
{
  int row = blockIdx.x * 4 + (threadIdx.x >> 6);
  int lane = threadIdx.x & 63;
  const float* xr = x + (size_t)row * DIM;
  float4 v[3];
  float s = 0.f, s2 = 0.f;
#pragma unroll
  for (int j = 0; j < 3; ++j){
    v[j] = *(const float4*)(xr + j * 256 + lane * 4);
    s  += v[j].x + v[j].y + v[j].z + v[j].w;
    s2 += v[j].x*v[j].x + v[j].y*v[j].y + v[j].z*v[j].z + v[j].w*v[j].w;
  }
#pragma unroll
  for (int m = 1; m < 64; m <<= 1){ s += __shfl_xor(s, m, 64); s2 += __shfl_xor(s2, m, 64); }
  float mu  = s * (1.f / 768.f);
  float var = s2 * (1.f / 768.f) - mu * mu;
  float inv = rsqrtf(var + 1e-5f);
#pragma unroll
  for (int j = 0; j < 3; ++j){
    int c0 = j * 256 + lane * 4;
    float vv[4] = { v[j].x, v[j].y, v[j].z, v[j].w };
    ushort4 o4;
    o4.x = f2bf((vv[0] - mu) * inv * g[c0 + 0] + b[c0 + 0]);
    o4.y = f2bf((vv[1] - mu) * inv * g[c0 + 1] + b[c0 + 1]);
    o4.z = f2bf((vv[2] - mu) * inv * g[c0 + 2] + b[c0 + 2]);
    o4.w = f2bf((vv[3] - mu) * inv * g[c0 + 3] + b[c0 + 3]);
    *(ushort4*)(out + (size_t)row * DIM + c0) = o4;
  }
}

// ------- fused weight transposes: 4 weights, W[K][N] fp32 -> Wt[N][K] bf16 ----------
__global__ __launch_bounds__(256) void transpose4_kernel(
    const float* __restrict__ w_qkv, const float* __restrict__ w_proj,
    const float* __restrict__ w_fc1, const float* __restrict__ w_fc2,
    unsigned short* __restrict__ tq, unsigned short* __restrict__ tp,
    unsigned short* __restrict__ t1, unsigned short* __restrict__ t2)
{
  __shared__ __align__(16) unsigned short tile[32][33];
  int id = blockIdx.x;
  const float* W; unsigned short* Wt; int K, N, tx_n;
  if (id < 1728)      { W = w_qkv;  Wt = tq; K = 768;  N = 2304; tx_n = 72; }
  else if (id < 2304) { W = w_proj; Wt = tp; K = 768;  N = 768;  tx_n = 24; id -= 1728; }
  else if (id < 4608) { W = w_fc1;  Wt = t1; K = 768;  N = 3072; tx_n = 96; id -= 2304; }
  else                { W = w_fc2;  Wt = t2; K = 3072; N = 768;  tx_n = 24; id -= 4608; }
  int n0 = (id % tx_n) * 32, k0 = (id / tx_n) * 32;
  int tx = threadIdx.x & 31, ty = threadIdx.x >> 5;
#pragma unroll
  for (int i = 0; i < 32; i += 8)
    tile[ty + i][tx] = f2bf(W[(size_t)(k0 + ty + i) * N + n0 + tx]);
  __syncthreads();
#pragma unroll
  for (int i = 0; i < 32; i += 8)
    Wt[(size_t)(n0 + ty + i) * K + k0 + tx] = tile[tx][ty + i];
}

// ---------------- pack attention mask into bit-words: pm[b][kt] bit k = mask!=0 ------
__global__ __launch_bounds__(256) void pack_mask_kernel(const int* __restrict__ am,
    unsigned long long* __restrict__ pm)
{
  int lane = threadIdx.x & 63, w = threadIdx.x >> 6, b = blockIdx.x;
  for (int k = w; k < 16; k += 4){
    unsigned long long m = __ballot(am[b * 1024 + k * 64 + lane] != 0);
    if (lane == 0) pm[b * 16 + k] = m;
  }
}

// ------- MFMA GEMM: triple-buffered, single-barrier, counted-vmcnt pipeline ---------
// EPI: 0 bias->bf16, 1 bias+GELU->bf16, 2 bias+resid->fp32, 3 QKV-split writer
template<int BM, int BN, int WM, int WN, int EPI, typename OutT>
__global__ __launch_bounds__(256) void gemm_kernel(
    const unsigned short* __restrict__ A,   // [M][K] bf16
    const unsigned short* __restrict__ Bt,  // [N][K] bf16
    const float* __restrict__ bias,         // [N]
    const float* __restrict__ resid,        // [M][N] (EPI==2)
    OutT* __restrict__ C,                   // [M][N]
    unsigned short* __restrict__ q_out,     // EPI==3
    unsigned short* __restrict__ k_out,
    unsigned short* __restrict__ v_out,
    int M, int N, int K)
{
  constexpr int BK = 32;
  constexpr int WAVES_N = BN / WN;
  constexpr int MI = WM / 16, NI = WN / 16;
  constexpr int ACH = BM * BK / 8, BCH = BN * BK / 8;
  constexpr int NC = (ACH + BCH) / 256;      // gload_lds instrs per wave per stage
  __shared__ __align__(16) unsigned short As[3][BM * BK];
  __shared__ __align__(16) unsigned short Bs[3][BN * BK];
  const int t = threadIdx.x, lane = t & 63, wid = t >> 6;
  const int lo = lane & 15, hi = lane >> 4;
  const int wr = wid / WAVES_N, wc = wid % WAVES_N;

  // bijective XCD swizzle (nwg % 8 == 0 for all our grids), row-major chunks
  const int gx = gridDim.x;
  const int nwg = gx * gridDim.y;
  const int lin = blockIdx.y * gx + blockIdx.x;
  const int swz = (lin & 7) * (nwg >> 3) + (lin >> 3);
  const int bm = (swz / gx) * BM, bn = (swz % gx) * BN;

  auto stage = [&](int buf, int k0){
#pragma unroll
    for (int u = 0; u < NC; ++u){
      int c = u * 256 + t;
      if (c < ACH){
        gload_lds16(A + (size_t)(bm + (c >> 2)) * K + k0 + (c & 3) * 8, &As[buf][c * 8]);
      } else {
        int c2 = c - ACH;
        gload_lds16(Bt + (size_t)(bn + (c2 >> 2)) * K + k0 + (c2 & 3) * 8, &Bs[buf][c2 * 8]);
      }
    }
  };

  f32x4 acc[MI][NI];
#pragma unroll
  for (int i = 0; i < MI; ++i)
#pragma unroll
    for (int j = 0; j < NI; ++j) acc[i][j] = (f32x4){0.f, 0.f, 0.f, 0.f};

  const int NIT = K / BK;
  stage(0, 0);
  stage(1, BK);
  for (int it = 0; it < NIT; ++it){
    // wait for tile `it` (ours); tile it+1's NC loads stay in flight
    if (it < NIT - 1) wait_vmcnt<NC>(); else wait_vmcnt<0>();
    __builtin_amdgcn_sched_barrier(0);
    __builtin_amdgcn_s_barrier();        // all waves: tile `it` fully staged
    __builtin_amdgcn_sched_barrier(0);
    if (it + 2 < NIT) stage((it + 2) % 3, (it + 2) * BK);  // flies under MFMA
    const unsigned short* as = As[it % 3];
    const unsigned short* bs = Bs[it % 3];
    bf16x8 af[MI], bfr[NI];
#pragma unroll
    for (int i = 0; i < MI; ++i)  af[i]  = *(const bf16x8*)&as[(wr * WM + i * 16 + lo) * BK + hi * 8];
#pragma unroll
    for (int j = 0; j < NI; ++j) bfr[j] = *(const bf16x8*)&bs[(wc * WN + j * 16 + lo) * BK + hi * 8];
#pragma unroll
    for (int i = 0; i < MI; ++i)
#pragma unroll
      for (int j = 0; j < NI; ++j)
        acc[i][j] = __builtin_amdgcn_mfma_f32_16x16x32_bf16(af[i], bfr[j], acc[i][j], 0, 0, 0);
  }

  // epilogue: C/D layout col = lane&15, row = (lane>>4)*4 + r
#pragma unroll
  for (int i = 0; i < MI; ++i){
#pragma unroll
    for (int j = 0; j < NI; ++j){
      int col = bn + wc * WN + j * 16 + lo;
      float bcol = bias[col];
      if constexpr (EPI == 3){
        int hh = (col % 768) >> 6, d = col & 63;
        int part = col / 768;
        int row0 = bm + wr * WM + i * 16 + hi * 4;
        int bb = row0 >> 10, n0 = row0 & 1023;
        size_t bh = (size_t)bb * 12 + hh;
        float v0 = acc[i][j][0] + bcol, v1 = acc[i][j][1] + bcol;
        float v2 = acc[i][j][2] + bcol, v3 = acc[i][j][3] + bcol;
        if (part == 0){
          q_out[(bh * 1024 + n0 + 0) * 64 + d] = f2bf(v0);
          q_out[(bh * 1024 + n0 + 1) * 64 + d] = f2bf(v1);
          q_out[(bh * 1024 + n0 + 2) * 64 + d] = f2bf(v2);
          q_out[(bh * 1024 + n0 + 3) * 64 + d] = f2bf(v3);
        } else if (part == 1){
          k_out[(bh * 1024 + n0 + 0) * 64 + d] = f2bf(v0);
          k_out[(bh * 1024 + n0 + 1) * 64 + d] = f2bf(v1);
          k_out[(bh * 1024 + n0 + 2) * 64 + d] = f2bf(v2);
          k_out[(bh * 1024 + n0 + 3) * 64 + d] = f2bf(v3);
        } else {
          unsigned w0 = cvt_pk_bf16(v0, v1), w1 = cvt_pk_bf16(v2, v3);
          *(uint2*)&v_out[bh * 65536 + (size_t)d * 1024 + n0] = make_uint2(w0, w1);
        }
      } else {
#pragma unroll
        for (int r = 0; r < 4; ++r){
          int row = bm + wr * WM + i * 16 + hi * 4 + r;
          float v = acc[i][j][r] + bcol;
          if constexpr (EPI == 1) v = 0.5f * v * (1.f + erff(v * 0.70710678118f));
          if constexpr (EPI == 2) v += resid[(size_t)row * N + col];
          if constexpr (sizeof(OutT) == 2) C[(size_t)row * N + col] = f2bf(v);
          else                             C[(size_t)row * N + col] = v;
        }
      }
    }
  }
}

// ---------------- Flash attention, swapped-operand (S^T = K·Q^T), fixed-max softmax --
__global__ __launch_bounds__(256) void attn_kernel(
    const unsigned short* __restrict__ Qs,   // [b*h][1024][64]
    const unsigned short* __restrict__ Ks,   // [b*h][1024][64]
    const unsigned short* __restrict__ Vts,  // [b*h][64][1024]  (V transposed)
    const unsigned long long* __restrict__ pm,
    unsigned short* __restrict__ o)          // [token][768]
{
  constexpr int LD = 72;
  __shared__ __align__(16) unsigned short Kl[64 * LD];
  __shared__ __align__(16) unsigned short Vt[64 * LD];
  __shared__ __align__(16) unsigned short Pl[4][16 * LD];
  const int qb = blockIdx.x, h = blockIdx.y, b = blockIdx.z;
  const int t = threadIdx.x, wid = t >> 6, lane = t & 63;
  const int lo = lane & 15, hi = lane >> 4;
  const size_t bh = (size_t)b * 12 + h;

  const unsigned short* Qg = Qs + (bh * 1024 + qb * 64 + wid * 16 + lo) * 64;
  bf16x8 qf0 = *(const bf16x8*)(Qg + hi * 8);
  bf16x8 qf1 = *(const bf16x8*)(Qg + 32 + hi * 8);

  f32x4 oacc[4];
#pragma unroll
  for (int dj = 0; dj < 4; ++dj) oacc[dj] = (f32x4){0.f, 0.f, 0.f, 0.f};
  float l_part = 0.f;

  const int srow = t >> 2, scol = (t & 3) * 16;
  const unsigned short* Kg = Ks  + bh * 65536;
  const unsigned short* Vg = Vts + bh * 65536;
  unsigned short* pw = &Pl[wid][0];

  for (int kt = 0; kt < 16; ++kt){
    __syncthreads();
    const unsigned short* kg = Kg + (kt * 64 + srow) * 64 + scol;
    *(bf16x8*)&Kl[srow * LD + scol]     = *(const bf16x8*)kg;
    *(bf16x8*)&Kl[srow * LD + scol + 8] = *(const bf16x8*)(kg + 8);
    const unsigned short* vg = Vg + srow * 1024 + kt * 64 + scol;
    *(bf16x8*)&Vt[srow * LD + scol]     = *(const bf16x8*)vg;
    *(bf16x8*)&Vt[srow * LD + scol + 8] = *(const bf16x8*)(vg + 8);
    __syncthreads();

    f32x4 s[4];
#pragma unroll
    for (int nj = 0; nj < 4; ++nj) s[nj] = (f32x4){0.f, 0.f, 0.f, 0.f};
#pragma unroll
    for (int kk = 0; kk < 2; ++kk){
      bf16x8 q = kk ? qf1 : qf0;
#pragma unroll
      for (int nj = 0; nj < 4; ++nj){
        bf16x8 kf = *(const bf16x8*)&Kl[(nj * 16 + lo) * LD + kk * 32 + hi * 8];
        s[nj] = __builtin_amdgcn_mfma_f32_16x16x32_bf16(kf, q, s[nj], 0, 0, 0);
      }
    }

    unsigned long long w = pm[b * 16 + kt] >> (hi * 4);
#pragma unroll
    for (int nj = 0; nj < 4; ++nj){
      float p[4];
#pragma unroll
      for (int r = 0; r < 4; ++r){
        float e = __expf(fmaf(s[nj][r], 0.125f, -16.0f));
        e = ((unsigned)(w >> (nj * 16 + r)) & 1u) ? e : 0.0f;
        l_part += e;
        p[r] = e;
      }
      unsigned w0 = cvt_pk_bf16(p[0], p[1]);
      unsigned w1 = cvt_pk_bf16(p[2], p[3]);
      *(uint2*)&pw[lo * LD + nj * 16 + hi * 4] = make_uint2(w0, w1);
    }
    asm volatile("" ::: "memory");
    bf16x8 pf0 = *(const bf16x8*)&pw[lo * LD + hi * 8];
    bf16x8 pf1 = *(const bf16x8*)&pw[lo * LD + 32 + hi * 8];
#pragma unroll
    for (int kk = 0; kk < 2; ++kk){
      bf16x8 pf = kk ? pf1 : pf0;
#pragma unroll
      for (int dj = 0; dj < 4; ++dj){
        bf16x8 vf = *(const bf16x8*)&Vt[(dj * 16 + lo) * LD + kk * 32 + hi * 8];
        oacc[dj] = __builtin_amdgcn_mfma_f32_16x16x32_bf16(vf, pf, oacc[dj], 0, 0, 0);
      }
    }
  }

  float l = l_part;
  l += __shfl_xor(l, 16, 64);
  l += __shfl_xor(l, 32, 64);
  float inv = 1.0f / l;
  size_t orow = (size_t)b * 1024 + qb * 64 + wid * 16 + lo;
#pragma unroll
  for (int dj = 0; dj < 4; ++dj){
    unsigned w0 = (unsigned)f2bf(oacc[dj][0] * inv) | ((unsigned)f2bf(oacc[dj][1] * inv) << 16);
    unsigned w1 = (unsigned)f2bf(oacc[dj][2] * inv) | ((unsigned)f2bf(oacc[dj][3] * inv) << 16);
    *(uint2*)&o[orow * DIM + h * 64 + dj * 16 + hi * 4] = make_uint2(w0, w1);
  }
}

extern "C" void kernel_launch(void* const* d_in, const int* in_sizes, int n_in,
                              void* d_out, int out_size, void* d_ws, size_t ws_size,
                              hipStream_t stream)
{
  const float* x      = (const float*)d_in[0];
  const int*   amask  = (const int*)  d_in[1];
  const float* ln1_g  = (const float*)d_in[2];
  const float* ln1_b  = (const float*)d_in[3];
  const float* ln2_g  = (const float*)d_in[4];
  const float* ln2_b  = (const float*)d_in[5];
  const float* w_qkv  = (const float*)d_in[6];
  const float* b_qkv  = (const float*)d_in[7];
  const float* w_proj = (const float*)d_in[8];
  const float* b_proj = (const float*)d_in[9];
  const float* w_fc1  = (const float*)d_in[10];
  const float* b_fc1  = (const float*)d_in[11];
  const float* w_fc2  = (const float*)d_in[12];
  const float* b_fc2  = (const float*)d_in[13];
  float* outp = (float*)d_out;

  char* w = (char*)d_ws;
  auto alloc = [&](size_t bytes){ char* p = w; w += (bytes + 255) & ~(size_t)255; return p; };

  char* p0 = alloc((size_t)4 * 6291456);
  unsigned short* Qs   = (unsigned short*)p0;
  unsigned short* Ks   = (unsigned short*)(p0 + 6291456);
  unsigned short* Vts  = (unsigned short*)(p0 + 2 * 6291456);
  unsigned short* o_bf = (unsigned short*)(p0 + 3 * 6291456);
  unsigned short* a1   = (unsigned short*)p0;
  unsigned short* h_bf = (unsigned short*)alloc((size_t)NTOK * DIM * 2);
  unsigned short* h2   = h_bf;
  float*          x1   = (float*)alloc((size_t)NTOK * DIM * 4);
  unsigned short* wqkvT = (unsigned short*)alloc((size_t)3 * DIM * DIM * 2);
  unsigned short* wprojT= (unsigned short*)alloc((size_t)DIM * DIM * 2);
  unsigned short* wfc1T = (unsigned short*)alloc((size_t)HID * DIM * 2);
  unsigned short* wfc2T = (unsigned short*)alloc((size_t)DIM * HID * 2);
  unsigned long long* pmask = (unsigned long long*)alloc(4 * 16 * 8);

  transpose4_kernel<<<6912, 256, 0, stream>>>(w_qkv, w_proj, w_fc1, w_fc2,
                                              wqkvT, wprojT, wfc1T, wfc2T);
  pack_mask_kernel<<<4, 256, 0, stream>>>(amask, pmask);

  ln_kernel<<<NTOK / 4, 256, 0, stream>>>(x, ln1_g, ln1_b, h_bf);
  gemm_kernel<128, 128, 64, 64, 3, unsigned short><<<dim3(2304 / 128, NTOK / 128), 256, 0, stream>>>(
      h_bf, wqkvT, b_qkv, nullptr, (unsigned short*)nullptr, Qs, Ks, Vts, NTOK, 2304, DIM);
  attn_kernel<<<dim3(16, 12, 4), 256, 0, stream>>>(Qs, Ks, Vts, pmask, o_bf);
  gemm_kernel<64, 64, 32, 32, 2, float><<<dim3(DIM / 64, NTOK / 64), 256, 0, stream>>>(
      o_bf, wprojT, b_proj, x, x1, nullptr, nullptr, nullptr, NTOK, DIM, DIM);
  ln_kernel<<<NTOK / 4, 256, 0, stream>>>(x1, ln2_g, ln2_b, h2);
  gemm_kernel<128, 128, 64, 64, 1, unsigned short><<<dim3(HID / 128, NTOK / 128), 256, 0, stream>>>(
      h2, wfc1T, b_fc1, nullptr, a1, nullptr, nullptr, nullptr, NTOK, HID, DIM);
  gemm_kernel<64, 64, 32, 32, 2, float><<<dim3(DIM / 64, NTOK / 64), 256, 0, stream>>>(
      a1, wfc2T, b_fc2, x1, outp, nullptr, nullptr, nullptr, NTOK, DIM, HID);
}

// Round 5
// 185.039 us; speedup vs baseline: 1.2636x; 1.0177x over previous
//
#include <hip/hip_runtime.h>

#define DIM 768
#define NTOK 4096
#define HID 3072

typedef __attribute__((ext_vector_type(8))) short bf16x8;
typedef __attribute__((ext_vector_type(4))) float f32x4;

__device__ inline unsigned short f2bf(float f){
  unsigned u = __float_as_uint(f);
  u += 0x7fff + ((u >> 16) & 1);
  return (unsigned short)(u >> 16);
}
__device__ inline unsigned cvt_pk_bf16(float a, float b){
  unsigned r;
  asm("v_cvt_pk_bf16_f32 %0, %1, %2" : "=v"(r) : "v"(a), "v"(b));
  return r;
}
__device__ inline void gload_lds16(const void* g, void* l){
  __builtin_amdgcn_global_load_lds(
      (const __attribute__((address_space(1))) unsigned int*)g,
      (__attribute__((address_space(3))) unsigned int*)l, 16, 0, 0);
}
template<int N> __device__ inline void wait_vmcnt(){
  if constexpr (N == 0) asm volatile("s_waitcnt vmcnt(0)" ::: "memory");
  else if constexpr (N == 2) asm volatile("s_waitcnt vmcnt(2)" ::: "memory");
  else if constexpr (N == 3) asm volatile("s_waitcnt vmcnt(3)" ::: "memory");
  else if constexpr (N == 4) asm volatile("s_waitcnt vmcnt(4)" ::: "memory");
  else static_assert(N == 0, "unsupported vmcnt");
}

// ---------------- LayerNorm: fp32 in -> bf16 out, 1 wave per 768-row ----------------
__global__ __launch_bounds__(256) void ln_kernel(const float* __restrict__ x,
    const float* __restrict__ g, const float* __restrict__ b,
    unsigned short* __restrict__ out)
{
  int row = blockIdx.x * 4 + (threadIdx.x >> 6);
  int lane = threadIdx.x & 63;
  const float* xr = x + (size_t)row * DIM;
  float4 v[3];
  float s = 0.f, s2 = 0.f;
#pragma unroll
  for (int j = 0; j < 3; ++j){
    v[j] = *(const float4*)(xr + j * 256 + lane * 4);
    s  += v[j].x + v[j].y + v[j].z + v[j].w;
    s2 += v[j].x*v[j].x + v[j].y*v[j].y + v[j].z*v[j].z + v[j].w*v[j].w;
  }
#pragma unroll
  for (int m = 1; m < 64; m <<= 1){ s += __shfl_xor(s, m, 64); s2 += __shfl_xor(s2, m, 64); }
  float mu  = s * (1.f / 768.f);
  float var = s2 * (1.f / 768.f) - mu * mu;
  float inv = rsqrtf(var + 1e-5f);
#pragma unroll
  for (int j = 0; j < 3; ++j){
    int c0 = j * 256 + lane * 4;
    float vv[4] = { v[j].x, v[j].y, v[j].z, v[j].w };
    ushort4 o4;
    o4.x = f2bf((vv[0] - mu) * inv * g[c0 + 0] + b[c0 + 0]);
    o4.y = f2bf((vv[1] - mu) * inv * g[c0 + 1] + b[c0 + 1]);
    o4.z = f2bf((vv[2] - mu) * inv * g[c0 + 2] + b[c0 + 2]);
    o4.w = f2bf((vv[3] - mu) * inv * g[c0 + 3] + b[c0 + 3]);
    *(ushort4*)(out + (size_t)row * DIM + c0) = o4;
  }
}

// ------- fused weight transposes: 4 weights, W[K][N] fp32 -> Wt[N][K] bf16 ----------
__global__ __launch_bounds__(256) void transpose4_kernel(
    const float* __restrict__ w_qkv, const float* __restrict__ w_proj,
    const float* __restrict__ w_fc1, const float* __restrict__ w_fc2,
    unsigned short* __restrict__ tq, unsigned short* __restrict__ tp,
    unsigned short* __restrict__ t1, unsigned short* __restrict__ t2)
{
  __shared__ __align__(16) unsigned short tile[32][33];
  int id = blockIdx.x;
  const float* W; unsigned short* Wt; int K, N, tx_n;
  if (id < 1728)      { W = w_qkv;  Wt = tq; K = 768;  N = 2304; tx_n = 72; }
  else if (id < 2304) { W = w_proj; Wt = tp; K = 768;  N = 768;  tx_n = 24; id -= 1728; }
  else if (id < 4608) { W = w_fc1;  Wt = t1; K = 768;  N = 3072; tx_n = 96; id -= 2304; }
  else                { W = w_fc2;  Wt = t2; K = 3072; N = 768;  tx_n = 24; id -= 4608; }
  int n0 = (id % tx_n) * 32, k0 = (id / tx_n) * 32;
  int tx = threadIdx.x & 31, ty = threadIdx.x >> 5;
#pragma unroll
  for (int i = 0; i < 32; i += 8)
    tile[ty + i][tx] = f2bf(W[(size_t)(k0 + ty + i) * N + n0 + tx]);
  __syncthreads();
#pragma unroll
  for (int i = 0; i < 32; i += 8)
    Wt[(size_t)(n0 + ty + i) * K + k0 + tx] = tile[tx][ty + i];
}

// ---------------- pack attention mask into bit-words: pm[b][kt] bit k = mask!=0 ------
__global__ __launch_bounds__(256) void pack_mask_kernel(const int* __restrict__ am,
    unsigned long long* __restrict__ pm)
{
  int lane = threadIdx.x & 63, w = threadIdx.x >> 6, b = blockIdx.x;
  for (int k = w; k < 16; k += 4){
    unsigned long long m = __ballot(am[b * 1024 + k * 64 + lane] != 0);
    if (lane == 0) pm[b * 16 + k] = m;
  }
}

// ------- MFMA GEMM: triple-buffered counted-vmcnt pipeline + LDS-staged epilogue ----
// EPI: 0 bias->bf16, 1 bias+GELU->bf16, 2 bias+resid->fp32, 3 QKV-split writer
template<int BM, int BN, int WM, int WN, int EPI, typename OutT>
__global__ __launch_bounds__(256) void gemm_kernel(
    const unsigned short* __restrict__ A,   // [M][K] bf16
    const unsigned short* __restrict__ Bt,  // [N][K] bf16
    const float* __restrict__ bias,         // [N]
    const float* __restrict__ resid,        // [M][N] (EPI==2)
    OutT* __restrict__ C,                   // [M][N]
    unsigned short* __restrict__ q_out,     // EPI==3
    unsigned short* __restrict__ k_out,
    unsigned short* __restrict__ v_out,
    int M, int N, int K)
{
  constexpr int BK = 32;
  constexpr int WAVES_N = BN / WN;
  constexpr int MI = WM / 16, NI = WN / 16;
  constexpr int ACH = BM * BK / 8, BCH = BN * BK / 8;
  constexpr int NC = (ACH + BCH) / 256;      // gload_lds instrs per wave per stage
  constexpr int STAGE_B = 3 * (BM + BN) * BK * 2;
  constexpr int EPI_B = (EPI == 2) ? BM * (BN + 4) * 4 : BM * (BN + 8) * 2;
  constexpr int SMEM_B = STAGE_B > EPI_B ? STAGE_B : EPI_B;
  __shared__ __align__(16) char smem[SMEM_B];
  auto As = (unsigned short(*)[BM * BK])smem;
  auto Bs = (unsigned short(*)[BN * BK])(smem + 3 * BM * BK * 2);
  const int t = threadIdx.x, lane = t & 63, wid = t >> 6;
  const int lo = lane & 15, hi = lane >> 4;
  const int wr = wid / WAVES_N, wc = wid % WAVES_N;

  // bijective XCD swizzle (nwg % 8 == 0 for all our grids), row-major chunks
  const int gx = gridDim.x;
  const int nwg = gx * gridDim.y;
  const int lin = blockIdx.y * gx + blockIdx.x;
  const int swz = (lin & 7) * (nwg >> 3) + (lin >> 3);
  const int bm = (swz / gx) * BM, bn = (swz % gx) * BN;

  auto stage = [&](int buf, int k0){
#pragma unroll
    for (int u = 0; u < NC; ++u){
      int c = u * 256 + t;
      if (c < ACH){
        gload_lds16(A + (size_t)(bm + (c >> 2)) * K + k0 + (c & 3) * 8, &As[buf][c * 8]);
      } else {
        int c2 = c - ACH;
        gload_lds16(Bt + (size_t)(bn + (c2 >> 2)) * K + k0 + (c2 & 3) * 8, &Bs[buf][c2 * 8]);
      }
    }
  };

  f32x4 acc[MI][NI];
#pragma unroll
  for (int i = 0; i < MI; ++i)
#pragma unroll
    for (int j = 0; j < NI; ++j) acc[i][j] = (f32x4){0.f, 0.f, 0.f, 0.f};

  const int NIT = K / BK;
  stage(0, 0);
  stage(1, BK);
  for (int it = 0; it < NIT; ++it){
    // wait for tile `it` (ours); tile it+1's NC loads stay in flight
    if (it < NIT - 1) wait_vmcnt<NC>(); else wait_vmcnt<0>();
    __builtin_amdgcn_sched_barrier(0);
    __builtin_amdgcn_s_barrier();        // all waves: tile `it` fully staged
    __builtin_amdgcn_sched_barrier(0);
    if (it + 2 < NIT) stage((it + 2) % 3, (it + 2) * BK);  // flies under MFMA
    const unsigned short* as = As[it % 3];
    const unsigned short* bs = Bs[it % 3];
    bf16x8 af[MI], bfr[NI];
#pragma unroll
    for (int i = 0; i < MI; ++i)  af[i]  = *(const bf16x8*)&as[(wr * WM + i * 16 + lo) * BK + hi * 8];
#pragma unroll
    for (int j = 0; j < NI; ++j) bfr[j] = *(const bf16x8*)&bs[(wc * WN + j * 16 + lo) * BK + hi * 8];
#pragma unroll
    for (int i = 0; i < MI; ++i)
#pragma unroll
      for (int j = 0; j < NI; ++j)
        acc[i][j] = __builtin_amdgcn_mfma_f32_16x16x32_bf16(af[i], bfr[j], acc[i][j], 0, 0, 0);
  }

  __syncthreads();   // all staging-LDS reads done; smem is reusable for the epilogue

  // ---- LDS-staged coalesced epilogue. acc layout: col=lane&15, row=(lane>>4)*4+r ----
  if constexpr (EPI == 2){
    constexpr int LDE = BN + 4;            // 68 floats, 272 B row (16B aligned)
    float* ET = (float*)smem;
#pragma unroll
    for (int i = 0; i < MI; ++i)
#pragma unroll
      for (int j = 0; j < NI; ++j){
        float bcol = bias[bn + wc * WN + j * 16 + lo];
#pragma unroll
        for (int r = 0; r < 4; ++r)
          ET[(wr * WM + i * 16 + hi * 4 + r) * LDE + wc * WN + j * 16 + lo] = acc[i][j][r] + bcol;
      }
    __syncthreads();
    int row = t >> 2, c0 = (t & 3) * 16;   // 256 threads cover 64 rows x 4 chunks
    const float* rrow = resid + (size_t)(bm + row) * N + bn + c0;
    float* crow = (float*)C + (size_t)(bm + row) * N + bn + c0;
#pragma unroll
    for (int k = 0; k < 4; ++k){
      float4 v = *(const float4*)&ET[row * LDE + c0 + k * 4];
      float4 rs = ((const float4*)rrow)[k];
      v.x += rs.x; v.y += rs.y; v.z += rs.z; v.w += rs.w;
      ((float4*)crow)[k] = v;
    }
  } else if constexpr (EPI == 0 || EPI == 1){
    constexpr int LDE = BN + 8;            // 136 bf16, 272 B row (16B aligned)
    unsigned short* ET = (unsigned short*)smem;
#pragma unroll
    for (int i = 0; i < MI; ++i)
#pragma unroll
      for (int j = 0; j < NI; ++j){
        float bcol = bias[bn + wc * WN + j * 16 + lo];
#pragma unroll
        for (int r = 0; r < 4; ++r){
          float v = acc[i][j][r] + bcol;
          if constexpr (EPI == 1) v = 0.5f * v * (1.f + erff(v * 0.70710678118f));
          ET[(wr * WM + i * 16 + hi * 4 + r) * LDE + wc * WN + j * 16 + lo] = f2bf(v);
        }
      }
    __syncthreads();
#pragma unroll
    for (int p = 0; p < BM / 16; ++p){     // 16 lanes x 16B = 256B-contiguous row runs
      int row = p * 16 + (t >> 4), chunk = t & 15;
      if (chunk * 8 < BN)
        *(bf16x8*)&((unsigned short*)C)[(size_t)(bm + row) * N + bn + chunk * 8] =
            *(const bf16x8*)&ET[row * LDE + chunk * 8];
    }
  } else {  // EPI == 3: QKV split. Tile (128 cols) lies in exactly one of Q/K/V.
    constexpr int LDE = BN + 8;            // 136
    unsigned short* ET = (unsigned short*)smem;
    const int part = bn / 768;             // 0=Q 1=K 2=V (uniform per block)
    const int cloc = bn % 768;
#pragma unroll
    for (int i = 0; i < MI; ++i)
#pragma unroll
      for (int j = 0; j < NI; ++j){
        int col_l = wc * WN + j * 16 + lo;
        float bcol = bias[bn + col_l];
#pragma unroll
        for (int r = 0; r < 4; ++r){
          int row_l = wr * WM + i * 16 + hi * 4 + r;
          unsigned short us = f2bf(acc[i][j][r] + bcol);
          if (part < 2) ET[row_l * LDE + col_l] = us;   // row-major for Q/K
          else          ET[col_l * LDE + row_l] = us;   // col-major for V (transposed out)
        }
      }
    __syncthreads();
    const int bb = bm >> 10, n0b = bm & 1023;           // tile is within one batch
    if (part < 2){
      unsigned short* dst0 = (part == 0) ? q_out : k_out;
#pragma unroll
      for (int p = 0; p < 8; ++p){
        int row = p * 16 + (t >> 4), chunk = t & 15;
        int hh = cloc / 64 + (chunk >> 3), d0 = (chunk & 7) * 8;
        unsigned short* dst = dst0 + ((size_t)(bb * 12 + hh)) * 65536 + (n0b + row) * 64 + d0;
        *(bf16x8*)dst = *(const bf16x8*)&ET[row * LDE + chunk * 8];
      }
    } else {
#pragma unroll
      for (int p = 0; p < 8; ++p){
        int colg = p * 16 + (t >> 4), chunk = t & 15;   // colg = local d index 0..127
        int hh = cloc / 64 + (colg >> 6), d = colg & 63;
        unsigned short* dst = v_out + ((size_t)(bb * 12 + hh)) * 65536 + (size_t)d * 1024 + n0b + chunk * 8;
        *(bf16x8*)dst = *(const bf16x8*)&ET[colg * LDE + chunk * 8];
      }
    }
  }
}

// ---------------- Flash attention, swapped-operand (S^T = K·Q^T), fixed-max softmax --
__global__ __launch_bounds__(256) void attn_kernel(
    const unsigned short* __restrict__ Qs,   // [b*h][1024][64]
    const unsigned short* __restrict__ Ks,   // [b*h][1024][64]
    const unsigned short* __restrict__ Vts,  // [b*h][64][1024]  (V transposed)
    const unsigned long long* __restrict__ pm,
    unsigned short* __restrict__ o)          // [token][768]
{
  constexpr int LD = 72;
  __shared__ __align__(16) unsigned short Kl[64 * LD];
  __shared__ __align__(16) unsigned short Vt[64 * LD];
  __shared__ __align__(16) unsigned short Pl[4][16 * LD];
  const int qb = blockIdx.x, h = blockIdx.y, b = blockIdx.z;
  const int t = threadIdx.x, wid = t >> 6, lane = t & 63;
  const int lo = lane & 15, hi = lane >> 4;
  const size_t bh = (size_t)b * 12 + h;

  const unsigned short* Qg = Qs + (bh * 1024 + qb * 64 + wid * 16 + lo) * 64;
  bf16x8 qf0 = *(const bf16x8*)(Qg + hi * 8);
  bf16x8 qf1 = *(const bf16x8*)(Qg + 32 + hi * 8);

  f32x4 oacc[4];
#pragma unroll
  for (int dj = 0; dj < 4; ++dj) oacc[dj] = (f32x4){0.f, 0.f, 0.f, 0.f};
  float l_part = 0.f;

  const int srow = t >> 2, scol = (t & 3) * 16;
  const unsigned short* Kg = Ks  + bh * 65536;
  const unsigned short* Vg = Vts + bh * 65536;
  unsigned short* pw = &Pl[wid][0];

  for (int kt = 0; kt < 16; ++kt){
    __syncthreads();
    const unsigned short* kg = Kg + (kt * 64 + srow) * 64 + scol;
    *(bf16x8*)&Kl[srow * LD + scol]     = *(const bf16x8*)kg;
    *(bf16x8*)&Kl[srow * LD + scol + 8] = *(const bf16x8*)(kg + 8);
    const unsigned short* vg = Vg + srow * 1024 + kt * 64 + scol;
    *(bf16x8*)&Vt[srow * LD + scol]     = *(const bf16x8*)vg;
    *(bf16x8*)&Vt[srow * LD + scol + 8] = *(const bf16x8*)(vg + 8);
    __syncthreads();

    f32x4 s[4];
#pragma unroll
    for (int nj = 0; nj < 4; ++nj) s[nj] = (f32x4){0.f, 0.f, 0.f, 0.f};
#pragma unroll
    for (int kk = 0; kk < 2; ++kk){
      bf16x8 q = kk ? qf1 : qf0;
#pragma unroll
      for (int nj = 0; nj < 4; ++nj){
        bf16x8 kf = *(const bf16x8*)&Kl[(nj * 16 + lo) * LD + kk * 32 + hi * 8];
        s[nj] = __builtin_amdgcn_mfma_f32_16x16x32_bf16(kf, q, s[nj], 0, 0, 0);
      }
    }

    unsigned long long w = pm[b * 16 + kt] >> (hi * 4);
#pragma unroll
    for (int nj = 0; nj < 4; ++nj){
      float p[4];
#pragma unroll
      for (int r = 0; r < 4; ++r){
        float e = __expf(fmaf(s[nj][r], 0.125f, -16.0f));
        e = ((unsigned)(w >> (nj * 16 + r)) & 1u) ? e : 0.0f;
        l_part += e;
        p[r] = e;
      }
      unsigned w0 = cvt_pk_bf16(p[0], p[1]);
      unsigned w1 = cvt_pk_bf16(p[2], p[3]);
      *(uint2*)&pw[lo * LD + nj * 16 + hi * 4] = make_uint2(w0, w1);
    }
    asm volatile("" ::: "memory");
    bf16x8 pf0 = *(const bf16x8*)&pw[lo * LD + hi * 8];
    bf16x8 pf1 = *(const bf16x8*)&pw[lo * LD + 32 + hi * 8];
#pragma unroll
    for (int kk = 0; kk < 2; ++kk){
      bf16x8 pf = kk ? pf1 : pf0;
#pragma unroll
      for (int dj = 0; dj < 4; ++dj){
        bf16x8 vf = *(const bf16x8*)&Vt[(dj * 16 + lo) * LD + kk * 32 + hi * 8];
        oacc[dj] = __builtin_amdgcn_mfma_f32_16x16x32_bf16(vf, pf, oacc[dj], 0, 0, 0);
      }
    }
  }

  float l = l_part;
  l += __shfl_xor(l, 16, 64);
  l += __shfl_xor(l, 32, 64);
  float inv = 1.0f / l;
  size_t orow = (size_t)b * 1024 + qb * 64 + wid * 16 + lo;
#pragma unroll
  for (int dj = 0; dj < 4; ++dj){
    unsigned w0 = (unsigned)f2bf(oacc[dj][0] * inv) | ((unsigned)f2bf(oacc[dj][1] * inv) << 16);
    unsigned w1 = (unsigned)f2bf(oacc[dj][2] * inv) | ((unsigned)f2bf(oacc[dj][3] * inv) << 16);
    *(uint2*)&o[orow * DIM + h * 64 + dj * 16 + hi * 4] = make_uint2(w0, w1);
  }
}

extern "C" void kernel_launch(void* const* d_in, const int* in_sizes, int n_in,
                              void* d_out, int out_size, void* d_ws, size_t ws_size,
                              hipStream_t stream)
{
  const float* x      = (const float*)d_in[0];
  const int*   amask  = (const int*)  d_in[1];
  const float* ln1_g  = (const float*)d_in[2];
  const float* ln1_b  = (const float*)d_in[3];
  const float* ln2_g  = (const float*)d_in[4];
  const float* ln2_b  = (const float*)d_in[5];
  const float* w_qkv  = (const float*)d_in[6];
  const float* b_qkv  = (const float*)d_in[7];
  const float* w_proj = (const float*)d_in[8];
  const float* b_proj = (const float*)d_in[9];
  const float* w_fc1  = (const float*)d_in[10];
  const float* b_fc1  = (const float*)d_in[11];
  const float* w_fc2  = (const float*)d_in[12];
  const float* b_fc2  = (const float*)d_in[13];
  float* outp = (float*)d_out;

  char* w = (char*)d_ws;
  auto alloc = [&](size_t bytes){ char* p = w; w += (bytes + 255) & ~(size_t)255; return p; };

  char* p0 = alloc((size_t)4 * 6291456);
  unsigned short* Qs   = (unsigned short*)p0;
  unsigned short* Ks   = (unsigned short*)(p0 + 6291456);
  unsigned short* Vts  = (unsigned short*)(p0 + 2 * 6291456);
  unsigned short* o_bf = (unsigned short*)(p0 + 3 * 6291456);
  unsigned short* a1   = (unsigned short*)p0;
  unsigned short* h_bf = (unsigned short*)alloc((size_t)NTOK * DIM * 2);
  unsigned short* h2   = h_bf;
  float*          x1   = (float*)alloc((size_t)NTOK * DIM * 4);
  unsigned short* wqkvT = (unsigned short*)alloc((size_t)3 * DIM * DIM * 2);
  unsigned short* wprojT= (unsigned short*)alloc((size_t)DIM * DIM * 2);
  unsigned short* wfc1T = (unsigned short*)alloc((size_t)HID * DIM * 2);
  unsigned short* wfc2T = (unsigned short*)alloc((size_t)DIM * HID * 2);
  unsigned long long* pmask = (unsigned long long*)alloc(4 * 16 * 8);

  transpose4_kernel<<<6912, 256, 0, stream>>>(w_qkv, w_proj, w_fc1, w_fc2,
                                              wqkvT, wprojT, wfc1T, wfc2T);
  pack_mask_kernel<<<4, 256, 0, stream>>>(amask, pmask);

  ln_kernel<<<NTOK / 4, 256, 0, stream>>>(x, ln1_g, ln1_b, h_bf);
  gemm_kernel<128, 128, 64, 64, 3, unsigned short><<<dim3(2304 / 128, NTOK / 128), 256, 0, stream>>>(
      h_bf, wqkvT, b_qkv, nullptr, (unsigned short*)nullptr, Qs, Ks, Vts, NTOK, 2304, DIM);
  attn_kernel<<<dim3(16, 12, 4), 256, 0, stream>>>(Qs, Ks, Vts, pmask, o_bf);
  gemm_kernel<64, 64, 32, 32, 2, float><<<dim3(DIM / 64, NTOK / 64), 256, 0, stream>>>(
      o_bf, wprojT, b_proj, x, x1, nullptr, nullptr, nullptr, NTOK, DIM, DIM);
  ln_kernel<<<NTOK / 4, 256, 0, stream>>>(x1, ln2_g, ln2_b, h2);
  gemm_kernel<128, 128, 64, 64, 1, unsigned short><<<dim3(HID / 128, NTOK / 128), 256, 0, stream>>>(
      h2, wfc1T, b_fc1, nullptr, a1, nullptr, nullptr, nullptr, NTOK, HID, DIM);
  gemm_kernel<64, 64, 32, 32, 2, float><<<dim3(DIM / 64, NTOK / 64), 256, 0, stream>>>(
      a1, wfc2T, b_fc2, x1, outp, nullptr, nullptr, nullptr, NTOK, DIM, HID);
}

// Round 6
// 183.505 us; speedup vs baseline: 1.2742x; 1.0084x over previous
//
#include <hip/hip_runtime.h>

#define DIM 768
#define NTOK 4096
#define HID 3072

typedef __attribute__((ext_vector_type(8))) short bf16x8;
typedef __attribute__((ext_vector_type(4))) float f32x4;

__device__ inline unsigned short f2bf(float f){
  unsigned u = __float_as_uint(f);
  u += 0x7fff + ((u >> 16) & 1);
  return (unsigned short)(u >> 16);
}
__device__ inline unsigned cvt_pk_bf16(float a, float b){
  unsigned r;
  asm("v_cvt_pk_bf16_f32 %0, %1, %2" : "=v"(r) : "v"(a), "v"(b));
  return r;
}
__device__ inline void gload_lds16(const void* g, void* l){
  __builtin_amdgcn_global_load_lds(
      (const __attribute__((address_space(1))) unsigned int*)g,
      (__attribute__((address_space(3))) unsigned int*)l, 16, 0, 0);
}
template<int N> __device__ inline void wait_vmcnt(){
  if constexpr (N == 0) asm volatile("s_waitcnt vmcnt(0)" ::: "memory");
  else if constexpr (N == 4) asm volatile("s_waitcnt vmcnt(4)" ::: "memory");
  else if constexpr (N == 8) asm volatile("s_waitcnt vmcnt(8)" ::: "memory");
  else static_assert(N == 0, "unsupported vmcnt");
}

// ---------------- LayerNorm: fp32 in -> bf16 out, 1 wave per 768-row ----------------
__global__ __launch_bounds__(256) void ln_kernel(const float* __restrict__ x,
    const float* __restrict__ g, const float* __restrict__ b,
    unsigned short* __restrict__ out)
{
  int row = blockIdx.x * 4 + (threadIdx.x >> 6);
  int lane = threadIdx.x & 63;
  const float* xr = x + (size_t)row * DIM;
  float4 v[3];
  float s = 0.f, s2 = 0.f;
#pragma unroll
  for (int j = 0; j < 3; ++j){
    v[j] = *(const float4*)(xr + j * 256 + lane * 4);
    s  += v[j].x + v[j].y + v[j].z + v[j].w;
    s2 += v[j].x*v[j].x + v[j].y*v[j].y + v[j].z*v[j].z + v[j].w*v[j].w;
  }
#pragma unroll
  for (int m = 1; m < 64; m <<= 1){ s += __shfl_xor(s, m, 64); s2 += __shfl_xor(s2, m, 64); }
  float mu  = s * (1.f / 768.f);
  float var = s2 * (1.f / 768.f) - mu * mu;
  float inv = rsqrtf(var + 1e-5f);
#pragma unroll
  for (int j = 0; j < 3; ++j){
    int c0 = j * 256 + lane * 4;
    float vv[4] = { v[j].x, v[j].y, v[j].z, v[j].w };
    ushort4 o4;
    o4.x = f2bf((vv[0] - mu) * inv * g[c0 + 0] + b[c0 + 0]);
    o4.y = f2bf((vv[1] - mu) * inv * g[c0 + 1] + b[c0 + 1]);
    o4.z = f2bf((vv[2] - mu) * inv * g[c0 + 2] + b[c0 + 2]);
    o4.w = f2bf((vv[3] - mu) * inv * g[c0 + 3] + b[c0 + 3]);
    *(ushort4*)(out + (size_t)row * DIM + c0) = o4;
  }
}

// ------- fused weight transposes: 4 weights, W[K][N] fp32 -> Wt[N][K] bf16 ----------
__global__ __launch_bounds__(256) void transpose4_kernel(
    const float* __restrict__ w_qkv, const float* __restrict__ w_proj,
    const float* __restrict__ w_fc1, const float* __restrict__ w_fc2,
    unsigned short* __restrict__ tq, unsigned short* __restrict__ tp,
    unsigned short* __restrict__ t1, unsigned short* __restrict__ t2)
{
  __shared__ __align__(16) unsigned short tile[32][33];
  int id = blockIdx.x;
  const float* W; unsigned short* Wt; int K, N, tx_n;
  if (id < 1728)      { W = w_qkv;  Wt = tq; K = 768;  N = 2304; tx_n = 72; }
  else if (id < 2304) { W = w_proj; Wt = tp; K = 768;  N = 768;  tx_n = 24; id -= 1728; }
  else if (id < 4608) { W = w_fc1;  Wt = t1; K = 768;  N = 3072; tx_n = 96; id -= 2304; }
  else                { W = w_fc2;  Wt = t2; K = 3072; N = 768;  tx_n = 24; id -= 4608; }
  int n0 = (id % tx_n) * 32, k0 = (id / tx_n) * 32;
  int tx = threadIdx.x & 31, ty = threadIdx.x >> 5;
#pragma unroll
  for (int i = 0; i < 32; i += 8)
    tile[ty + i][tx] = f2bf(W[(size_t)(k0 + ty + i) * N + n0 + tx]);
  __syncthreads();
#pragma unroll
  for (int i = 0; i < 32; i += 8)
    Wt[(size_t)(n0 + ty + i) * K + k0 + tx] = tile[tx][ty + i];
}

// ---------------- pack attention mask into bit-words: pm[b][kt] bit k = mask!=0 ------
__global__ __launch_bounds__(256) void pack_mask_kernel(const int* __restrict__ am,
    unsigned long long* __restrict__ pm)
{
  int lane = threadIdx.x & 63, w = threadIdx.x >> 6, b = blockIdx.x;
  for (int k = w; k < 16; k += 4){
    unsigned long long m = __ballot(am[b * 1024 + k * 64 + lane] != 0);
    if (lane == 0) pm[b * 16 + k] = m;
  }
}

// ------- MFMA GEMM 128x128, DEPTH-buffered counted-vmcnt pipeline, LDS epilogue -----
// EPI: 0 bias->bf16, 1 bias+GELU->bf16, 2 bias+resid->fp32, 3 QKV-split writer
template<int DEPTH, int EPI, typename OutT>
__global__ __launch_bounds__(256) void gemm_kernel(
    const unsigned short* __restrict__ A,   // [M][K] bf16
    const unsigned short* __restrict__ Bt,  // [N][K] bf16
    const float* __restrict__ bias,         // [N]
    const float* __restrict__ resid,        // [M][N] (EPI==2)
    OutT* __restrict__ C,                   // [M][N]
    unsigned short* __restrict__ q_out,     // EPI==3
    unsigned short* __restrict__ k_out,
    unsigned short* __restrict__ v_out,
    int M, int N, int K)
{
  constexpr int BM = 128, BN = 128, BK = 32, WM = 64, WN = 64;
  constexpr int WAVES_N = BN / WN;           // 2
  constexpr int MI = WM / 16, NI = WN / 16;  // 4, 4
  constexpr int ACH = BM * BK / 8, BCH = BN * BK / 8;   // 512, 512
  constexpr int NC = (ACH + BCH) / 256;      // 4 gload_lds per thread per stage
  constexpr int SMEM_B = DEPTH * (BM + BN) * BK * 2;    // 48KB (D=3) / 64KB (D=4)
  __shared__ __align__(16) char smem[SMEM_B];
  auto As = (unsigned short(*)[BM * BK])smem;
  auto Bs = (unsigned short(*)[BN * BK])(smem + DEPTH * BM * BK * 2);
  const int t = threadIdx.x, lane = t & 63, wid = t >> 6;
  const int lo = lane & 15, hi = lane >> 4;
  const int wr = wid / WAVES_N, wc = wid % WAVES_N;

  // bijective XCD swizzle (nwg % 8 == 0 for all our grids), row-major chunks
  const int gx = gridDim.x;
  const int nwg = gx * gridDim.y;
  const int lin = blockIdx.y * gx + blockIdx.x;
  const int swz = (lin & 7) * (nwg >> 3) + (lin >> 3);
  const int bm = (swz / gx) * BM, bn = (swz % gx) * BN;

  auto stage = [&](int buf, int k0){
#pragma unroll
    for (int u = 0; u < NC; ++u){
      int c = u * 256 + t;
      if (c < ACH){
        gload_lds16(A + (size_t)(bm + (c >> 2)) * K + k0 + (c & 3) * 8, &As[buf][c * 8]);
      } else {
        int c2 = c - ACH;
        gload_lds16(Bt + (size_t)(bn + (c2 >> 2)) * K + k0 + (c2 & 3) * 8, &Bs[buf][c2 * 8]);
      }
    }
  };

  f32x4 acc[MI][NI];
#pragma unroll
  for (int i = 0; i < MI; ++i)
#pragma unroll
    for (int j = 0; j < NI; ++j) acc[i][j] = (f32x4){0.f, 0.f, 0.f, 0.f};

  const int NIT = K / BK;
#pragma unroll
  for (int d = 0; d < DEPTH - 1; ++d) stage(d, d * BK);
  for (int it = 0; it < NIT; ++it){
    // wait for tile `it` (ours); up to DEPTH-2 later tiles stay in flight
    int rem = NIT - 1 - it;
    if (rem >= DEPTH - 2) wait_vmcnt<(DEPTH - 2) * NC>();
    else if (DEPTH == 4 && rem == 1) wait_vmcnt<NC>();
    else wait_vmcnt<0>();
    __builtin_amdgcn_sched_barrier(0);
    __builtin_amdgcn_s_barrier();        // all waves: tile `it` fully staged
    __builtin_amdgcn_sched_barrier(0);
    if (it + DEPTH - 1 < NIT) stage((it + DEPTH - 1) % DEPTH, (it + DEPTH - 1) * BK);
    const unsigned short* as = As[it % DEPTH];
    const unsigned short* bs = Bs[it % DEPTH];
    bf16x8 af[MI], bfr[NI];
#pragma unroll
    for (int i = 0; i < MI; ++i)  af[i]  = *(const bf16x8*)&as[(wr * WM + i * 16 + lo) * BK + hi * 8];
#pragma unroll
    for (int j = 0; j < NI; ++j) bfr[j] = *(const bf16x8*)&bs[(wc * WN + j * 16 + lo) * BK + hi * 8];
#pragma unroll
    for (int i = 0; i < MI; ++i)
#pragma unroll
      for (int j = 0; j < NI; ++j)
        acc[i][j] = __builtin_amdgcn_mfma_f32_16x16x32_bf16(af[i], bfr[j], acc[i][j], 0, 0, 0);
  }

  __syncthreads();   // all staging-LDS reads done; smem is reusable for the epilogue

  // ---- LDS-staged coalesced epilogue. acc layout: col=lane&15, row=(lane>>4)*4+r ----
  if constexpr (EPI == 2){
    // fp32 + resid, two 64-row halves (wr==half waves own those rows)
    constexpr int LDE = BN + 4;            // 132 floats
    float* ET = (float*)smem;
#pragma unroll
    for (int half = 0; half < 2; ++half){
      if (wr == half){
#pragma unroll
        for (int i = 0; i < MI; ++i)
#pragma unroll
          for (int j = 0; j < NI; ++j){
            float bcol = bias[bn + wc * WN + j * 16 + lo];
#pragma unroll
            for (int r = 0; r < 4; ++r)
              ET[(i * 16 + hi * 4 + r) * LDE + wc * WN + j * 16 + lo] = acc[i][j][r] + bcol;
          }
      }
      __syncthreads();
      int lrow = t >> 2, gg = t & 3;       // 64 rows x 4 col-groups
      const float* rrow = resid + (size_t)(bm + half * 64 + lrow) * N + bn;
      float* crow = (float*)C + (size_t)(bm + half * 64 + lrow) * N + bn;
#pragma unroll
      for (int k = 0; k < 8; ++k){
        int c4 = (gg + k * 4) * 4;         // lanes 0-3 cover 64B contiguous
        float4 v = *(const float4*)&ET[lrow * LDE + c4];
        float4 rs = *(const float4*)&rrow[c4];
        v.x += rs.x; v.y += rs.y; v.z += rs.z; v.w += rs.w;
        *(float4*)&crow[c4] = v;
      }
      if (half == 0) __syncthreads();
    }
  } else if constexpr (EPI == 0 || EPI == 1){
    constexpr int LDE = BN + 8;            // 136 bf16, 272 B row
    unsigned short* ET = (unsigned short*)smem;
#pragma unroll
    for (int i = 0; i < MI; ++i)
#pragma unroll
      for (int j = 0; j < NI; ++j){
        float bcol = bias[bn + wc * WN + j * 16 + lo];
#pragma unroll
        for (int r = 0; r < 4; ++r){
          float v = acc[i][j][r] + bcol;
          if constexpr (EPI == 1) v = 0.5f * v * (1.f + erff(v * 0.70710678118f));
          ET[(wr * WM + i * 16 + hi * 4 + r) * LDE + wc * WN + j * 16 + lo] = f2bf(v);
        }
      }
    __syncthreads();
#pragma unroll
    for (int p = 0; p < BM / 16; ++p){     // 16 lanes x 16B = 256B-contiguous row runs
      int row = p * 16 + (t >> 4), chunk = t & 15;
      *(bf16x8*)&((unsigned short*)C)[(size_t)(bm + row) * N + bn + chunk * 8] =
          *(const bf16x8*)&ET[row * LDE + chunk * 8];
    }
  } else {  // EPI == 3: QKV split. Tile (128 cols) lies in exactly one of Q/K/V.
    constexpr int LDE = BN + 8;            // 136
    unsigned short* ET = (unsigned short*)smem;
    const int part = bn / 768;             // 0=Q 1=K 2=V (uniform per block)
    const int cloc = bn % 768;
#pragma unroll
    for (int i = 0; i < MI; ++i)
#pragma unroll
      for (int j = 0; j < NI; ++j){
        int col_l = wc * WN + j * 16 + lo;
        float bcol = bias[bn + col_l];
#pragma unroll
        for (int r = 0; r < 4; ++r){
          int row_l = wr * WM + i * 16 + hi * 4 + r;
          unsigned short us = f2bf(acc[i][j][r] + bcol);
          if (part < 2) ET[row_l * LDE + col_l] = us;   // row-major for Q/K
          else          ET[col_l * LDE + row_l] = us;   // col-major for V (transposed out)
        }
      }
    __syncthreads();
    const int bb = bm >> 10, n0b = bm & 1023;           // tile is within one batch
    if (part < 2){
      unsigned short* dst0 = (part == 0) ? q_out : k_out;
#pragma unroll
      for (int p = 0; p < 8; ++p){
        int row = p * 16 + (t >> 4), chunk = t & 15;
        int hh = cloc / 64 + (chunk >> 3), d0 = (chunk & 7) * 8;
        unsigned short* dst = dst0 + ((size_t)(bb * 12 + hh)) * 65536 + (n0b + row) * 64 + d0;
        *(bf16x8*)dst = *(const bf16x8*)&ET[row * LDE + chunk * 8];
      }
    } else {
#pragma unroll
      for (int p = 0; p < 8; ++p){
        int colg = p * 16 + (t >> 4), chunk = t & 15;   // colg = local d index 0..127
        int hh = cloc / 64 + (colg >> 6), d = colg & 63;
        unsigned short* dst = v_out + ((size_t)(bb * 12 + hh)) * 65536 + (size_t)d * 1024 + n0b + chunk * 8;
        *(bf16x8*)dst = *(const bf16x8*)&ET[colg * LDE + chunk * 8];
      }
    }
  }
}

// ---------------- Flash attention, swapped-operand (S^T = K·Q^T), fixed-max softmax --
__global__ __launch_bounds__(256) void attn_kernel(
    const unsigned short* __restrict__ Qs,   // [b*h][1024][64]
    const unsigned short* __restrict__ Ks,   // [b*h][1024][64]
    const unsigned short* __restrict__ Vts,  // [b*h][64][1024]  (V transposed)
    const unsigned long long* __restrict__ pm,
    unsigned short* __restrict__ o)          // [token][768]
{
  constexpr int LD = 72;
  __shared__ __align__(16) unsigned short Kl[64 * LD];
  __shared__ __align__(16) unsigned short Vt[64 * LD];
  __shared__ __align__(16) unsigned short Pl[4][16 * LD];
  const int qb = blockIdx.x, h = blockIdx.y, b = blockIdx.z;
  const int t = threadIdx.x, wid = t >> 6, lane = t & 63;
  const int lo = lane & 15, hi = lane >> 4;
  const size_t bh = (size_t)b * 12 + h;

  const unsigned short* Qg = Qs + (bh * 1024 + qb * 64 + wid * 16 + lo) * 64;
  bf16x8 qf0 = *(const bf16x8*)(Qg + hi * 8);
  bf16x8 qf1 = *(const bf16x8*)(Qg + 32 + hi * 8);

  f32x4 oacc[4];
#pragma unroll
  for (int dj = 0; dj < 4; ++dj) oacc[dj] = (f32x4){0.f, 0.f, 0.f, 0.f};
  float l_part = 0.f;

  const int srow = t >> 2, scol = (t & 3) * 16;
  const unsigned short* Kg = Ks  + bh * 65536;
  const unsigned short* Vg = Vts + bh * 65536;
  unsigned short* pw = &Pl[wid][0];

  for (int kt = 0; kt < 16; ++kt){
    __syncthreads();
    const unsigned short* kg = Kg + (kt * 64 + srow) * 64 + scol;
    *(bf16x8*)&Kl[srow * LD + scol]     = *(const bf16x8*)kg;
    *(bf16x8*)&Kl[srow * LD + scol + 8] = *(const bf16x8*)(kg + 8);
    const unsigned short* vg = Vg + srow * 1024 + kt * 64 + scol;
    *(bf16x8*)&Vt[srow * LD + scol]     = *(const bf16x8*)vg;
    *(bf16x8*)&Vt[srow * LD + scol + 8] = *(const bf16x8*)(vg + 8);
    __syncthreads();

    f32x4 s[4];
#pragma unroll
    for (int nj = 0; nj < 4; ++nj) s[nj] = (f32x4){0.f, 0.f, 0.f, 0.f};
#pragma unroll
    for (int kk = 0; kk < 2; ++kk){
      bf16x8 q = kk ? qf1 : qf0;
#pragma unroll
      for (int nj = 0; nj < 4; ++nj){
        bf16x8 kf = *(const bf16x8*)&Kl[(nj * 16 + lo) * LD + kk * 32 + hi * 8];
        s[nj] = __builtin_amdgcn_mfma_f32_16x16x32_bf16(kf, q, s[nj], 0, 0, 0);
      }
    }

    unsigned long long w = pm[b * 16 + kt] >> (hi * 4);
#pragma unroll
    for (int nj = 0; nj < 4; ++nj){
      float p[4];
#pragma unroll
      for (int r = 0; r < 4; ++r){
        float e = __expf(fmaf(s[nj][r], 0.125f, -16.0f));
        e = ((unsigned)(w >> (nj * 16 + r)) & 1u) ? e : 0.0f;
        l_part += e;
        p[r] = e;
      }
      unsigned w0 = cvt_pk_bf16(p[0], p[1]);
      unsigned w1 = cvt_pk_bf16(p[2], p[3]);
      *(uint2*)&pw[lo * LD + nj * 16 + hi * 4] = make_uint2(w0, w1);
    }
    asm volatile("" ::: "memory");
    bf16x8 pf0 = *(const bf16x8*)&pw[lo * LD + hi * 8];
    bf16x8 pf1 = *(const bf16x8*)&pw[lo * LD + 32 + hi * 8];
#pragma unroll
    for (int kk = 0; kk < 2; ++kk){
      bf16x8 pf = kk ? pf1 : pf0;
#pragma unroll
      for (int dj = 0; dj < 4; ++dj){
        bf16x8 vf = *(const bf16x8*)&Vt[(dj * 16 + lo) * LD + kk * 32 + hi * 8];
        oacc[dj] = __builtin_amdgcn_mfma_f32_16x16x32_bf16(vf, pf, oacc[dj], 0, 0, 0);
      }
    }
  }

  float l = l_part;
  l += __shfl_xor(l, 16, 64);
  l += __shfl_xor(l, 32, 64);
  float inv = 1.0f / l;
  size_t orow = (size_t)b * 1024 + qb * 64 + wid * 16 + lo;
#pragma unroll
  for (int dj = 0; dj < 4; ++dj){
    unsigned w0 = (unsigned)f2bf(oacc[dj][0] * inv) | ((unsigned)f2bf(oacc[dj][1] * inv) << 16);
    unsigned w1 = (unsigned)f2bf(oacc[dj][2] * inv) | ((unsigned)f2bf(oacc[dj][3] * inv) << 16);
    *(uint2*)&o[orow * DIM + h * 64 + dj * 16 + hi * 4] = make_uint2(w0, w1);
  }
}

extern "C" void kernel_launch(void* const* d_in, const int* in_sizes, int n_in,
                              void* d_out, int out_size, void* d_ws, size_t ws_size,
                              hipStream_t stream)
{
  const float* x      = (const float*)d_in[0];
  const int*   amask  = (const int*)  d_in[1];
  const float* ln1_g  = (const float*)d_in[2];
  const float* ln1_b  = (const float*)d_in[3];
  const float* ln2_g  = (const float*)d_in[4];
  const float* ln2_b  = (const float*)d_in[5];
  const float* w_qkv  = (const float*)d_in[6];
  const float* b_qkv  = (const float*)d_in[7];
  const float* w_proj = (const float*)d_in[8];
  const float* b_proj = (const float*)d_in[9];
  const float* w_fc1  = (const float*)d_in[10];
  const float* b_fc1  = (const float*)d_in[11];
  const float* w_fc2  = (const float*)d_in[12];
  const float* b_fc2  = (const float*)d_in[13];
  float* outp = (float*)d_out;

  char* w = (char*)d_ws;
  auto alloc = [&](size_t bytes){ char* p = w; w += (bytes + 255) & ~(size_t)255; return p; };

  char* p0 = alloc((size_t)4 * 6291456);
  unsigned short* Qs   = (unsigned short*)p0;
  unsigned short* Ks   = (unsigned short*)(p0 + 6291456);
  unsigned short* Vts  = (unsigned short*)(p0 + 2 * 6291456);
  unsigned short* o_bf = (unsigned short*)(p0 + 3 * 6291456);
  unsigned short* a1   = (unsigned short*)p0;
  unsigned short* h_bf = (unsigned short*)alloc((size_t)NTOK * DIM * 2);
  unsigned short* h2   = h_bf;
  float*          x1   = (float*)alloc((size_t)NTOK * DIM * 4);
  unsigned short* wqkvT = (unsigned short*)alloc((size_t)3 * DIM * DIM * 2);
  unsigned short* wprojT= (unsigned short*)alloc((size_t)DIM * DIM * 2);
  unsigned short* wfc1T = (unsigned short*)alloc((size_t)HID * DIM * 2);
  unsigned short* wfc2T = (unsigned short*)alloc((size_t)DIM * HID * 2);
  unsigned long long* pmask = (unsigned long long*)alloc(4 * 16 * 8);

  transpose4_kernel<<<6912, 256, 0, stream>>>(w_qkv, w_proj, w_fc1, w_fc2,
                                              wqkvT, wprojT, wfc1T, wfc2T);
  pack_mask_kernel<<<4, 256, 0, stream>>>(amask, pmask);

  ln_kernel<<<NTOK / 4, 256, 0, stream>>>(x, ln1_g, ln1_b, h_bf);
  gemm_kernel<3, 3, unsigned short><<<dim3(2304 / 128, NTOK / 128), 256, 0, stream>>>(
      h_bf, wqkvT, b_qkv, nullptr, (unsigned short*)nullptr, Qs, Ks, Vts, NTOK, 2304, DIM);
  attn_kernel<<<dim3(16, 12, 4), 256, 0, stream>>>(Qs, Ks, Vts, pmask, o_bf);
  gemm_kernel<4, 2, float><<<dim3(DIM / 128, NTOK / 128), 256, 0, stream>>>(
      o_bf, wprojT, b_proj, x, x1, nullptr, nullptr, nullptr, NTOK, DIM, DIM);
  ln_kernel<<<NTOK / 4, 256, 0, stream>>>(x1, ln2_g, ln2_b, h2);
  gemm_kernel<3, 1, unsigned short><<<dim3(HID / 128, NTOK / 128), 256, 0, stream>>>(
      h2, wfc1T, b_fc1, nullptr, a1, nullptr, nullptr, nullptr, NTOK, HID, DIM);
  gemm_kernel<4, 2, float><<<dim3(DIM / 128, NTOK / 128), 256, 0, stream>>>(
      a1, wfc2T, b_fc2, x1, outp, nullptr, nullptr, nullptr, NTOK, DIM, HID);
}

// Round 7
// 177.637 us; speedup vs baseline: 1.3163x; 1.0330x over previous
//
#include <hip/hip_runtime.h>

#define DIM 768
#define NTOK 4096
#define HID 3072

typedef __attribute__((ext_vector_type(8))) short bf16x8;
typedef __attribute__((ext_vector_type(4))) float f32x4;

__device__ inline unsigned short f2bf(float f){
  unsigned u = __float_as_uint(f);
  u += 0x7fff + ((u >> 16) & 1);
  return (unsigned short)(u >> 16);
}
__device__ inline unsigned cvt_pk_bf16(float a, float b){
  unsigned r;
  asm("v_cvt_pk_bf16_f32 %0, %1, %2" : "=v"(r) : "v"(a), "v"(b));
  return r;
}
__device__ inline void gload_lds16(const void* g, void* l){
  __builtin_amdgcn_global_load_lds(
      (const __attribute__((address_space(1))) unsigned int*)g,
      (__attribute__((address_space(3))) unsigned int*)l, 16, 0, 0);
}
template<int N> __device__ inline void wait_vmcnt(){
  if constexpr (N == 0) asm volatile("s_waitcnt vmcnt(0)" ::: "memory");
  else if constexpr (N == 2) asm volatile("s_waitcnt vmcnt(2)" ::: "memory");
  else if constexpr (N == 4) asm volatile("s_waitcnt vmcnt(4)" ::: "memory");
  else if constexpr (N == 6) asm volatile("s_waitcnt vmcnt(6)" ::: "memory");
  else if constexpr (N == 8) asm volatile("s_waitcnt vmcnt(8)" ::: "memory");
  else static_assert(N == 0, "unsupported vmcnt");
}

// ---------------- LayerNorm: fp32 in -> bf16 out, 1 wave per 768-row ----------------
__global__ __launch_bounds__(256) void ln_kernel(const float* __restrict__ x,
    const float* __restrict__ g, const float* __restrict__ b,
    unsigned short* __restrict__ out)
{
  int row = blockIdx.x * 4 + (threadIdx.x >> 6);
  int lane = threadIdx.x & 63;
  const float* xr = x + (size_t)row * DIM;
  float4 v[3];
  float s = 0.f, s2 = 0.f;
#pragma unroll
  for (int j = 0; j < 3; ++j){
    v[j] = *(const float4*)(xr + j * 256 + lane * 4);
    s  += v[j].x + v[j].y + v[j].z + v[j].w;
    s2 += v[j].x*v[j].x + v[j].y*v[j].y + v[j].z*v[j].z + v[j].w*v[j].w;
  }
#pragma unroll
  for (int m = 1; m < 64; m <<= 1){ s += __shfl_xor(s, m, 64); s2 += __shfl_xor(s2, m, 64); }
  float mu  = s * (1.f / 768.f);
  float var = s2 * (1.f / 768.f) - mu * mu;
  float inv = rsqrtf(var + 1e-5f);
#pragma unroll
  for (int j = 0; j < 3; ++j){
    int c0 = j * 256 + lane * 4;
    float vv[4] = { v[j].x, v[j].y, v[j].z, v[j].w };
    ushort4 o4;
    o4.x = f2bf((vv[0] - mu) * inv * g[c0 + 0] + b[c0 + 0]);
    o4.y = f2bf((vv[1] - mu) * inv * g[c0 + 1] + b[c0 + 1]);
    o4.z = f2bf((vv[2] - mu) * inv * g[c0 + 2] + b[c0 + 2]);
    o4.w = f2bf((vv[3] - mu) * inv * g[c0 + 3] + b[c0 + 3]);
    *(ushort4*)(out + (size_t)row * DIM + c0) = o4;
  }
}

// ------- fused weight transposes: 4 weights, W[K][N] fp32 -> Wt[N][K] bf16 ----------
__global__ __launch_bounds__(256) void transpose4_kernel(
    const float* __restrict__ w_qkv, const float* __restrict__ w_proj,
    const float* __restrict__ w_fc1, const float* __restrict__ w_fc2,
    unsigned short* __restrict__ tq, unsigned short* __restrict__ tp,
    unsigned short* __restrict__ t1, unsigned short* __restrict__ t2)
{
  __shared__ __align__(16) unsigned short tile[32][33];
  int id = blockIdx.x;
  const float* W; unsigned short* Wt; int K, N, tx_n;
  if (id < 1728)      { W = w_qkv;  Wt = tq; K = 768;  N = 2304; tx_n = 72; }
  else if (id < 2304) { W = w_proj; Wt = tp; K = 768;  N = 768;  tx_n = 24; id -= 1728; }
  else if (id < 4608) { W = w_fc1;  Wt = t1; K = 768;  N = 3072; tx_n = 96; id -= 2304; }
  else                { W = w_fc2;  Wt = t2; K = 3072; N = 768;  tx_n = 24; id -= 4608; }
  int n0 = (id % tx_n) * 32, k0 = (id / tx_n) * 32;
  int tx = threadIdx.x & 31, ty = threadIdx.x >> 5;
#pragma unroll
  for (int i = 0; i < 32; i += 8)
    tile[ty + i][tx] = f2bf(W[(size_t)(k0 + ty + i) * N + n0 + tx]);
  __syncthreads();
#pragma unroll
  for (int i = 0; i < 32; i += 8)
    Wt[(size_t)(n0 + ty + i) * K + k0 + tx] = tile[tx][ty + i];
}

// ---------------- pack attention mask into bit-words: pm[b][kt] bit k = mask!=0 ------
__global__ __launch_bounds__(256) void pack_mask_kernel(const int* __restrict__ am,
    unsigned long long* __restrict__ pm)
{
  int lane = threadIdx.x & 63, w = threadIdx.x >> 6, b = blockIdx.x;
  for (int k = w; k < 16; k += 4){
    unsigned long long m = __ballot(am[b * 1024 + k * 64 + lane] != 0);
    if (lane == 0) pm[b * 16 + k] = m;
  }
}

// ------- 256-thread MFMA GEMM (QKV / FC1): DEPTH-buffered counted-vmcnt pipeline ----
// EPI: 0 bias->bf16, 1 bias+GELU->bf16, 3 QKV-split writer
template<int DEPTH, int EPI, typename OutT>
__global__ __launch_bounds__(256) void gemm_kernel(
    const unsigned short* __restrict__ A,   // [M][K] bf16
    const unsigned short* __restrict__ Bt,  // [N][K] bf16
    const float* __restrict__ bias,         // [N]
    const float* __restrict__ resid,        // unused
    OutT* __restrict__ C,                   // [M][N]
    unsigned short* __restrict__ q_out,     // EPI==3
    unsigned short* __restrict__ k_out,
    unsigned short* __restrict__ v_out,
    int M, int N, int K)
{
  constexpr int BM = 128, BN = 128, BK = 32, WM = 64, WN = 64;
  constexpr int WAVES_N = BN / WN;           // 2
  constexpr int MI = WM / 16, NI = WN / 16;  // 4, 4
  constexpr int ACH = BM * BK / 8, BCH = BN * BK / 8;   // 512, 512
  constexpr int NC = (ACH + BCH) / 256;      // 4 gload_lds per thread per stage
  constexpr int SMEM_B = DEPTH * (BM + BN) * BK * 2;
  __shared__ __align__(16) char smem[SMEM_B];
  auto As = (unsigned short(*)[BM * BK])smem;
  auto Bs = (unsigned short(*)[BN * BK])(smem + DEPTH * BM * BK * 2);
  const int t = threadIdx.x, lane = t & 63, wid = t >> 6;
  const int lo = lane & 15, hi = lane >> 4;
  const int wr = wid / WAVES_N, wc = wid % WAVES_N;

  // bijective XCD swizzle (nwg % 8 == 0 for all our grids), row-major chunks
  const int gx = gridDim.x;
  const int nwg = gx * gridDim.y;
  const int lin = blockIdx.y * gx + blockIdx.x;
  const int swz = (lin & 7) * (nwg >> 3) + (lin >> 3);
  const int bm = (swz / gx) * BM, bn = (swz % gx) * BN;

  auto stage = [&](int buf, int k0){
#pragma unroll
    for (int u = 0; u < NC; ++u){
      int c = u * 256 + t;
      if (c < ACH){
        gload_lds16(A + (size_t)(bm + (c >> 2)) * K + k0 + (c & 3) * 8, &As[buf][c * 8]);
      } else {
        int c2 = c - ACH;
        gload_lds16(Bt + (size_t)(bn + (c2 >> 2)) * K + k0 + (c2 & 3) * 8, &Bs[buf][c2 * 8]);
      }
    }
  };

  f32x4 acc[MI][NI];
#pragma unroll
  for (int i = 0; i < MI; ++i)
#pragma unroll
    for (int j = 0; j < NI; ++j) acc[i][j] = (f32x4){0.f, 0.f, 0.f, 0.f};

  const int NIT = K / BK;
#pragma unroll
  for (int d = 0; d < DEPTH - 1; ++d) stage(d, d * BK);
  for (int it = 0; it < NIT; ++it){
    int rem = NIT - 1 - it;
    if (rem >= DEPTH - 2) wait_vmcnt<(DEPTH - 2) * NC>();
    else if (DEPTH == 4 && rem == 1) wait_vmcnt<NC>();
    else wait_vmcnt<0>();
    __builtin_amdgcn_sched_barrier(0);
    __builtin_amdgcn_s_barrier();        // all waves: tile `it` fully staged
    __builtin_amdgcn_sched_barrier(0);
    if (it + DEPTH - 1 < NIT) stage((it + DEPTH - 1) % DEPTH, (it + DEPTH - 1) * BK);
    const unsigned short* as = As[it % DEPTH];
    const unsigned short* bs = Bs[it % DEPTH];
    bf16x8 af[MI], bfr[NI];
#pragma unroll
    for (int i = 0; i < MI; ++i)  af[i]  = *(const bf16x8*)&as[(wr * WM + i * 16 + lo) * BK + hi * 8];
#pragma unroll
    for (int j = 0; j < NI; ++j) bfr[j] = *(const bf16x8*)&bs[(wc * WN + j * 16 + lo) * BK + hi * 8];
#pragma unroll
    for (int i = 0; i < MI; ++i)
#pragma unroll
      for (int j = 0; j < NI; ++j)
        acc[i][j] = __builtin_amdgcn_mfma_f32_16x16x32_bf16(af[i], bfr[j], acc[i][j], 0, 0, 0);
  }

  __syncthreads();   // all staging-LDS reads done; smem is reusable for the epilogue

  // ---- LDS-staged coalesced epilogue. acc layout: col=lane&15, row=(lane>>4)*4+r ----
  if constexpr (EPI == 0 || EPI == 1){
    constexpr int LDE = BN + 8;            // 136 bf16, 272 B row
    unsigned short* ET = (unsigned short*)smem;
#pragma unroll
    for (int i = 0; i < MI; ++i)
#pragma unroll
      for (int j = 0; j < NI; ++j){
        float bcol = bias[bn + wc * WN + j * 16 + lo];
#pragma unroll
        for (int r = 0; r < 4; ++r){
          float v = acc[i][j][r] + bcol;
          if constexpr (EPI == 1) v = 0.5f * v * (1.f + erff(v * 0.70710678118f));
          ET[(wr * WM + i * 16 + hi * 4 + r) * LDE + wc * WN + j * 16 + lo] = f2bf(v);
        }
      }
    __syncthreads();
#pragma unroll
    for (int p = 0; p < BM / 16; ++p){     // 16 lanes x 16B = 256B-contiguous row runs
      int row = p * 16 + (t >> 4), chunk = t & 15;
      *(bf16x8*)&((unsigned short*)C)[(size_t)(bm + row) * N + bn + chunk * 8] =
          *(const bf16x8*)&ET[row * LDE + chunk * 8];
    }
  } else {  // EPI == 3: QKV split. Tile (128 cols) lies in exactly one of Q/K/V.
    constexpr int LDE = BN + 8;            // 136
    unsigned short* ET = (unsigned short*)smem;
    const int part = bn / 768;             // 0=Q 1=K 2=V (uniform per block)
    const int cloc = bn % 768;
#pragma unroll
    for (int i = 0; i < MI; ++i)
#pragma unroll
      for (int j = 0; j < NI; ++j){
        int col_l = wc * WN + j * 16 + lo;
        float bcol = bias[bn + col_l];
#pragma unroll
        for (int r = 0; r < 4; ++r){
          int row_l = wr * WM + i * 16 + hi * 4 + r;
          unsigned short us = f2bf(acc[i][j][r] + bcol);
          if (part < 2) ET[row_l * LDE + col_l] = us;   // row-major for Q/K
          else          ET[col_l * LDE + row_l] = us;   // col-major for V (transposed out)
        }
      }
    __syncthreads();
    const int bb = bm >> 10, n0b = bm & 1023;           // tile is within one batch
    if (part < 2){
      unsigned short* dst0 = (part == 0) ? q_out : k_out;
#pragma unroll
      for (int p = 0; p < 8; ++p){
        int row = p * 16 + (t >> 4), chunk = t & 15;
        int hh = cloc / 64 + (chunk >> 3), d0 = (chunk & 7) * 8;
        unsigned short* dst = dst0 + ((size_t)(bb * 12 + hh)) * 65536 + (n0b + row) * 64 + d0;
        *(bf16x8*)dst = *(const bf16x8*)&ET[row * LDE + chunk * 8];
      }
    } else {
#pragma unroll
      for (int p = 0; p < 8; ++p){
        int colg = p * 16 + (t >> 4), chunk = t & 15;   // colg = local d index 0..127
        int hh = cloc / 64 + (colg >> 6), d = colg & 63;
        unsigned short* dst = v_out + ((size_t)(bb * 12 + hh)) * 65536 + (size_t)d * 1024 + n0b + chunk * 8;
        *(bf16x8*)dst = *(const bf16x8*)&ET[colg * LDE + chunk * 8];
      }
    }
  }
}

// ------- 512-thread MFMA GEMM for N=768 (proj, FC2): BM=128 x BN=96, 8 waves --------
// grid = (N/96) x (M/128) = 8 x 32 = 256 blocks: exactly 1/CU, 2 waves/SIMD.
// out = A @ Bt^T + bias + resid (fp32)
template<int DEPTH>
__global__ __launch_bounds__(512) void gemm512_kernel(
    const unsigned short* __restrict__ A,   // [M][K] bf16
    const unsigned short* __restrict__ Bt,  // [N][K] bf16
    const float* __restrict__ bias,         // [N]
    const float* __restrict__ resid,        // [M][N]
    float* __restrict__ C,                  // [M][N]
    int M, int N, int K)
{
  constexpr int BM = 128, BN = 96, BK = 32;
  constexpr int MI = 2, NI = 3;            // wave tile 32x48, wave grid 4x2
  constexpr int ACH = BM * BK / 8;         // 512 16B chunks
  constexpr int BCH = BN * BK / 8;         // 384
  constexpr int NC = 2;                    // gload_lds per thread per stage (padded)
  constexpr int SMEM_B = DEPTH * (BM + BN) * BK * 2;    // 14336*DEPTH
  __shared__ __align__(16) char smem[SMEM_B];
  auto As = (unsigned short(*)[BM * BK])smem;
  auto Bs = (unsigned short(*)[BN * BK])(smem + DEPTH * BM * BK * 2);
  const int t = threadIdx.x, lane = t & 63, wid = t >> 6;
  const int lo = lane & 15, hi = lane >> 4;
  const int wr = wid >> 1, wc = wid & 1;   // 4 row-waves x 2 col-waves

  const int gx = gridDim.x;
  const int nwg = gx * gridDim.y;
  const int lin = blockIdx.y * gx + blockIdx.x;
  const int swz = (lin & 7) * (nwg >> 3) + (lin >> 3);
  const int bm = (swz / gx) * BM, bn = (swz % gx) * BN;

  auto stage = [&](int buf, int k0){
#pragma unroll
    for (int u = 0; u < NC; ++u){
      int c = u * 512 + t;
      if (c < ACH){
        gload_lds16(A + (size_t)(bm + (c >> 2)) * K + k0 + (c & 3) * 8, &As[buf][c * 8]);
      } else {
        int c2 = c - ACH;
        if (c2 >= BCH) c2 -= BCH;          // waves 6,7 round 2: benign duplicate stage
        gload_lds16(Bt + (size_t)(bn + (c2 >> 2)) * K + k0 + (c2 & 3) * 8, &Bs[buf][c2 * 8]);
      }
    }
  };

  f32x4 acc[MI][NI];
#pragma unroll
  for (int i = 0; i < MI; ++i)
#pragma unroll
    for (int j = 0; j < NI; ++j) acc[i][j] = (f32x4){0.f, 0.f, 0.f, 0.f};

  const int NIT = K / BK;
#pragma unroll
  for (int d = 0; d < DEPTH - 1; ++d) stage(d, d * BK);
  for (int it = 0; it < NIT; ++it){
    int rem = NIT - 1 - it;
    if (rem >= DEPTH - 2) wait_vmcnt<(DEPTH - 2) * NC>();
    else if (rem == 3)    wait_vmcnt<6>();
    else if (rem == 2)    wait_vmcnt<4>();
    else if (rem == 1)    wait_vmcnt<2>();
    else                  wait_vmcnt<0>();
    __builtin_amdgcn_sched_barrier(0);
    __builtin_amdgcn_s_barrier();          // tile `it` fully staged
    __builtin_amdgcn_sched_barrier(0);
    if (it + DEPTH - 1 < NIT) stage((it + DEPTH - 1) % DEPTH, (it + DEPTH - 1) * BK);
    const unsigned short* as = As[it % DEPTH];
    const unsigned short* bs = Bs[it % DEPTH];
    bf16x8 af[MI], bfr[NI];
#pragma unroll
    for (int i = 0; i < MI; ++i)  af[i]  = *(const bf16x8*)&as[(wr * 32 + i * 16 + lo) * BK + hi * 8];
#pragma unroll
    for (int j = 0; j < NI; ++j) bfr[j] = *(const bf16x8*)&bs[(wc * 48 + j * 16 + lo) * BK + hi * 8];
#pragma unroll
    for (int i = 0; i < MI; ++i)
#pragma unroll
      for (int j = 0; j < NI; ++j)
        acc[i][j] = __builtin_amdgcn_mfma_f32_16x16x32_bf16(af[i], bfr[j], acc[i][j], 0, 0, 0);
  }

  __syncthreads();   // staging reads done; reuse smem for fp32 epilogue tile
  constexpr int LDE = BN + 4;              // 100 floats, 400 B rows (16B aligned)
  static_assert(BM * LDE * 4 <= SMEM_B, "epilogue tile must fit");
  float* ET = (float*)smem;
#pragma unroll
  for (int i = 0; i < MI; ++i)
#pragma unroll
    for (int j = 0; j < NI; ++j){
      int col_l = wc * 48 + j * 16 + lo;
      float bcol = bias[bn + col_l];
#pragma unroll
      for (int r = 0; r < 4; ++r)
        ET[(wr * 32 + i * 16 + hi * 4 + r) * LDE + col_l] = acc[i][j][r] + bcol;
    }
  __syncthreads();
  {
    int row = t >> 2, q = t & 3;           // 128 rows x 4 col-groups, 6 float4 each
    const float* rrow = resid + (size_t)(bm + row) * N + bn;
    float* crow = C + (size_t)(bm + row) * N + bn;
#pragma unroll
    for (int k = 0; k < 6; ++k){
      int c4 = (q + k * 4) * 4;
      float4 v = *(const float4*)&ET[row * LDE + c4];
      float4 rs = *(const float4*)&rrow[c4];
      v.x += rs.x; v.y += rs.y; v.z += rs.z; v.w += rs.w;
      *(float4*)&crow[c4] = v;
    }
  }
}

// ---------------- Flash attention, swapped-operand (S^T = K·Q^T), fixed-max softmax --
__global__ __launch_bounds__(256) void attn_kernel(
    const unsigned short* __restrict__ Qs,   // [b*h][1024][64]
    const unsigned short* __restrict__ Ks,   // [b*h][1024][64]
    const unsigned short* __restrict__ Vts,  // [b*h][64][1024]  (V transposed)
    const unsigned long long* __restrict__ pm,
    unsigned short* __restrict__ o)          // [token][768]
{
  constexpr int LD = 72;
  __shared__ __align__(16) unsigned short Kl[64 * LD];
  __shared__ __align__(16) unsigned short Vt[64 * LD];
  __shared__ __align__(16) unsigned short Pl[4][16 * LD];
  const int qb = blockIdx.x, h = blockIdx.y, b = blockIdx.z;
  const int t = threadIdx.x, wid = t >> 6, lane = t & 63;
  const int lo = lane & 15, hi = lane >> 4;
  const size_t bh = (size_t)b * 12 + h;

  const unsigned short* Qg = Qs + (bh * 1024 + qb * 64 + wid * 16 + lo) * 64;
  bf16x8 qf0 = *(const bf16x8*)(Qg + hi * 8);
  bf16x8 qf1 = *(const bf16x8*)(Qg + 32 + hi * 8);

  f32x4 oacc[4];
#pragma unroll
  for (int dj = 0; dj < 4; ++dj) oacc[dj] = (f32x4){0.f, 0.f, 0.f, 0.f};
  float l_part = 0.f;

  const int srow = t >> 2, scol = (t & 3) * 16;
  const unsigned short* Kg = Ks  + bh * 65536;
  const unsigned short* Vg = Vts + bh * 65536;
  unsigned short* pw = &Pl[wid][0];

  for (int kt = 0; kt < 16; ++kt){
    __syncthreads();
    const unsigned short* kg = Kg + (kt * 64 + srow) * 64 + scol;
    *(bf16x8*)&Kl[srow * LD + scol]     = *(const bf16x8*)kg;
    *(bf16x8*)&Kl[srow * LD + scol + 8] = *(const bf16x8*)(kg + 8);
    const unsigned short* vg = Vg + srow * 1024 + kt * 64 + scol;
    *(bf16x8*)&Vt[srow * LD + scol]     = *(const bf16x8*)vg;
    *(bf16x8*)&Vt[srow * LD + scol + 8] = *(const bf16x8*)(vg + 8);
    __syncthreads();

    f32x4 s[4];
#pragma unroll
    for (int nj = 0; nj < 4; ++nj) s[nj] = (f32x4){0.f, 0.f, 0.f, 0.f};
#pragma unroll
    for (int kk = 0; kk < 2; ++kk){
      bf16x8 q = kk ? qf1 : qf0;
#pragma unroll
      for (int nj = 0; nj < 4; ++nj){
        bf16x8 kf = *(const bf16x8*)&Kl[(nj * 16 + lo) * LD + kk * 32 + hi * 8];
        s[nj] = __builtin_amdgcn_mfma_f32_16x16x32_bf16(kf, q, s[nj], 0, 0, 0);
      }
    }

    unsigned long long w = pm[b * 16 + kt] >> (hi * 4);
#pragma unroll
    for (int nj = 0; nj < 4; ++nj){
      float p[4];
#pragma unroll
      for (int r = 0; r < 4; ++r){
        float e = __expf(fmaf(s[nj][r], 0.125f, -16.0f));
        e = ((unsigned)(w >> (nj * 16 + r)) & 1u) ? e : 0.0f;
        l_part += e;
        p[r] = e;
      }
      unsigned w0 = cvt_pk_bf16(p[0], p[1]);
      unsigned w1 = cvt_pk_bf16(p[2], p[3]);
      *(uint2*)&pw[lo * LD + nj * 16 + hi * 4] = make_uint2(w0, w1);
    }
    asm volatile("" ::: "memory");
    bf16x8 pf0 = *(const bf16x8*)&pw[lo * LD + hi * 8];
    bf16x8 pf1 = *(const bf16x8*)&pw[lo * LD + 32 + hi * 8];
#pragma unroll
    for (int kk = 0; kk < 2; ++kk){
      bf16x8 pf = kk ? pf1 : pf0;
#pragma unroll
      for (int dj = 0; dj < 4; ++dj){
        bf16x8 vf = *(const bf16x8*)&Vt[(dj * 16 + lo) * LD + kk * 32 + hi * 8];
        oacc[dj] = __builtin_amdgcn_mfma_f32_16x16x32_bf16(vf, pf, oacc[dj], 0, 0, 0);
      }
    }
  }

  float l = l_part;
  l += __shfl_xor(l, 16, 64);
  l += __shfl_xor(l, 32, 64);
  float inv = 1.0f / l;
  size_t orow = (size_t)b * 1024 + qb * 64 + wid * 16 + lo;
#pragma unroll
  for (int dj = 0; dj < 4; ++dj){
    unsigned w0 = (unsigned)f2bf(oacc[dj][0] * inv) | ((unsigned)f2bf(oacc[dj][1] * inv) << 16);
    unsigned w1 = (unsigned)f2bf(oacc[dj][2] * inv) | ((unsigned)f2bf(oacc[dj][3] * inv) << 16);
    *(uint2*)&o[orow * DIM + h * 64 + dj * 16 + hi * 4] = make_uint2(w0, w1);
  }
}

extern "C" void kernel_launch(void* const* d_in, const int* in_sizes, int n_in,
                              void* d_out, int out_size, void* d_ws, size_t ws_size,
                              hipStream_t stream)
{
  const float* x      = (const float*)d_in[0];
  const int*   amask  = (const int*)  d_in[1];
  const float* ln1_g  = (const float*)d_in[2];
  const float* ln1_b  = (const float*)d_in[3];
  const float* ln2_g  = (const float*)d_in[4];
  const float* ln2_b  = (const float*)d_in[5];
  const float* w_qkv  = (const float*)d_in[6];
  const float* b_qkv  = (const float*)d_in[7];
  const float* w_proj = (const float*)d_in[8];
  const float* b_proj = (const float*)d_in[9];
  const float* w_fc1  = (const float*)d_in[10];
  const float* b_fc1  = (const float*)d_in[11];
  const float* w_fc2  = (const float*)d_in[12];
  const float* b_fc2  = (const float*)d_in[13];
  float* outp = (float*)d_out;

  char* w = (char*)d_ws;
  auto alloc = [&](size_t bytes){ char* p = w; w += (bytes + 255) & ~(size_t)255; return p; };

  char* p0 = alloc((size_t)4 * 6291456);
  unsigned short* Qs   = (unsigned short*)p0;
  unsigned short* Ks   = (unsigned short*)(p0 + 6291456);
  unsigned short* Vts  = (unsigned short*)(p0 + 2 * 6291456);
  unsigned short* o_bf = (unsigned short*)(p0 + 3 * 6291456);
  unsigned short* a1   = (unsigned short*)p0;
  unsigned short* h_bf = (unsigned short*)alloc((size_t)NTOK * DIM * 2);
  unsigned short* h2   = h_bf;
  float*          x1   = (float*)alloc((size_t)NTOK * DIM * 4);
  unsigned short* wqkvT = (unsigned short*)alloc((size_t)3 * DIM * DIM * 2);
  unsigned short* wprojT= (unsigned short*)alloc((size_t)DIM * DIM * 2);
  unsigned short* wfc1T = (unsigned short*)alloc((size_t)HID * DIM * 2);
  unsigned short* wfc2T = (unsigned short*)alloc((size_t)DIM * HID * 2);
  unsigned long long* pmask = (unsigned long long*)alloc(4 * 16 * 8);

  transpose4_kernel<<<6912, 256, 0, stream>>>(w_qkv, w_proj, w_fc1, w_fc2,
                                              wqkvT, wprojT, wfc1T, wfc2T);
  pack_mask_kernel<<<4, 256, 0, stream>>>(amask, pmask);

  ln_kernel<<<NTOK / 4, 256, 0, stream>>>(x, ln1_g, ln1_b, h_bf);
  gemm_kernel<3, 3, unsigned short><<<dim3(2304 / 128, NTOK / 128), 256, 0, stream>>>(
      h_bf, wqkvT, b_qkv, nullptr, (unsigned short*)nullptr, Qs, Ks, Vts, NTOK, 2304, DIM);
  attn_kernel<<<dim3(16, 12, 4), 256, 0, stream>>>(Qs, Ks, Vts, pmask, o_bf);
  gemm512_kernel<4><<<dim3(DIM / 96, NTOK / 128), 512, 0, stream>>>(
      o_bf, wprojT, b_proj, x, x1, NTOK, DIM, DIM);
  ln_kernel<<<NTOK / 4, 256, 0, stream>>>(x1, ln2_g, ln2_b, h2);
  gemm_kernel<3, 1, unsigned short><<<dim3(HID / 128, NTOK / 128), 256, 0, stream>>>(
      h2, wfc1T, b_fc1, nullptr, a1, nullptr, nullptr, nullptr, NTOK, HID, DIM);
  gemm512_kernel<6><<<dim3(DIM / 96, NTOK / 128), 512, 0, stream>>>(
      a1, wfc2T, b_fc2, x1, outp, NTOK, DIM, HID);
}